// Round 10
// baseline (2511.656 us; speedup 1.0000x reference)
//
#include <hip/hip_runtime.h>

// ===========================================================================
// GAT_CNN_DASE :: gfx950 :: R20.
// R19 post-mortem: 128^2 2-blocks/CU REGRESSED (241us, MfmaUtil 33%, FETCH
// 556MB) -> desync-overlap falsified; smaller tile = more LDS/FLOP + A-refetch.
// Unified model (fits R13..R19 + m201): wall/iter = MFMA + LDS-read, SUMMED.
// 256^2: 4966 + 4600 = 9566cy model vs 9160 meas (util 47 pred/45 meas).
// Only remaining lever: fewer LDS-read bytes.
// R20: B out of LDS -> per-wave B-register streaming from global (B panels
// L2/L3-hot; frag = contiguous 16B/lane at BT[col*ldb + k + quad*8]).
// LDS reads 48->32 per wave/iter (-33%); LDS 128->64KB; A-gloads 8/iter.
// New ledger (A-events only): WAIT4 at every even phase -- each target slab
// has exactly 4 younger A-events (in-order retirement => landed; interleaved
// B-reg loads only strengthen the wait). Peel drains 4->2->0. B dbuf in
// rb0/rb1, loaded 1 K-32 slot ahead. Same MFMA order -> numerics unchanged.
// hh2 aliases feats (dead after L1).
// ===========================================================================

typedef unsigned short u16;
typedef __attribute__((ext_vector_type(8))) short bf16x8;
typedef __attribute__((ext_vector_type(4))) float f32x4;

__device__ __forceinline__ float b2f(u16 u) {
  unsigned v = ((unsigned)u) << 16;
  return __builtin_bit_cast(float, v);
}
__device__ __forceinline__ u16 f2b(float f) {
  unsigned x = __builtin_bit_cast(unsigned, f);
  x += 0x7fffu + ((x >> 16) & 1u);
  return (u16)(x >> 16);
}

// async global->LDS, 16B per lane; LDS dest = wave-uniform base + lane*16
__device__ __forceinline__ void async_ld16(const u16* g, u16* l) {
  __builtin_amdgcn_global_load_lds(
      (const __attribute__((address_space(1))) void*)g,
      (__attribute__((address_space(3))) void*)l, 16, 0, 0);
}

// bf16 data: ~100% of u16s have exponent in [100,140]; f32-as-u16: ~58%.
__device__ __forceinline__ int sniff_bf16(const void* p, int n) {
  const u16* pu = (const u16*)p;
  int ns = n < 128 ? n : 128;
  int sane = 0, nz = 0;
  for (int i = 0; i < ns; i++) {
    u16 v = pu[i];
    if (v) nz++;
    int e = (v >> 7) & 0xFF;
    if (e >= 100 && e <= 140) sane++;
  }
  return (nz == 0) || (sane * 8 >= ns * 7);
}
__device__ __forceinline__ float ld_any(const void* p, size_t i, int isbf) {
  return isbf ? b2f(((const u16*)p)[i]) : ((const float*)p)[i];
}

__global__ void cvt_f(const void* __restrict__ in, float* __restrict__ out,
                      int n) {
  __shared__ int sbf;
  if (threadIdx.x == 0) sbf = sniff_bf16(in, n);
  __syncthreads();
  int tid = blockIdx.x * 256 + threadIdx.x;
  if (tid < n) out[tid] = ld_any(in, tid, sbf);
}
// in[k*N+n] -> out[n*K+k] (small front-end weights)
__global__ void cvt_f_t(const void* __restrict__ in, float* __restrict__ out,
                        int K, int N) {
  __shared__ int sbf;
  if (threadIdx.x == 0) sbf = sniff_bf16(in, K * N);
  __syncthreads();
  int tid = blockIdx.x * 256 + threadIdx.x;
  if (tid >= K * N) return;
  int nn = tid / K, k = tid - nn * K;
  out[tid] = ld_any(in, (size_t)k * N + nn, sbf);
}
__global__ void cvt_b(const void* __restrict__ in, u16* __restrict__ out,
                      int n) {
  __shared__ int sbf;
  if (threadIdx.x == 0) sbf = sniff_bf16(in, n);
  __syncthreads();
  int tid = blockIdx.x * 256 + threadIdx.x;
  if (tid < n) out[tid] = f2b(ld_any(in, tid, sbf));
}
// tiled transpose-convert: in K x N -> out Npad x Kpad bf16, zero-padded.
__global__ void cvt_b_tt(const void* __restrict__ in, u16* __restrict__ out,
                         int K, int N, int Kpad, int Npad) {
  __shared__ int sbf;
  __shared__ float tile[32][33];
  if (threadIdx.x == 0) sbf = sniff_bf16(in, K * N);
  __syncthreads();
  int k0 = blockIdx.x * 32, n0 = blockIdx.y * 32;
  int tx = threadIdx.x & 31, ty = threadIdx.x >> 5;  // 32x8
#pragma unroll
  for (int i = 0; i < 32; i += 8) {
    int k = k0 + ty + i, n = n0 + tx;
    tile[ty + i][tx] =
        (k < K && n < N) ? ld_any(in, (size_t)k * N + n, sbf) : 0.f;
  }
  __syncthreads();
#pragma unroll
  for (int i = 0; i < 32; i += 8) {
    int n = n0 + ty + i, k = k0 + tx;
    if (n < Npad && k < Kpad) out[(size_t)n * Kpad + k] = f2b(tile[tx][ty + i]);
  }
}

// ---------------------------------------------------------------------------
// feats chunk: feats[r][0..2784) = emb[p0[..]] * emb[1500+p1[..]], cols
// 2784..2816 zeroed (K padded to 2816 for BK=64). One thread per 8 elems.
// ---------------------------------------------------------------------------
__global__ void k_feats(const u16* __restrict__ emb,
                        const int* __restrict__ posp,
                        const int* __restrict__ negp, int npos, int mbase,
                        int rows, u16* __restrict__ feats) {
  int idx = blockIdx.x * 256 + threadIdx.x;
  int r = idx / 352, c8 = (idx - r * 352) * 8;
  if (r >= rows) return;
  if (c8 >= 2784) {
    bf16x8 z = {0, 0, 0, 0, 0, 0, 0, 0};
    *(bf16x8*)(feats + (size_t)r * 2816 + c8) = z;
    return;
  }
  int g = mbase + r;
  const int* pp = (g < npos) ? (posp + 2 * g) : (negp + 2 * (g - npos));
  bf16x8 x = *(const bf16x8*)(emb + (size_t)pp[0] * 2784 + c8);
  bf16x8 y = *(const bf16x8*)(emb + (size_t)(1500 + pp[1]) * 2784 + c8);
  bf16x8 v;
#pragma unroll
  for (int j = 0; j < 8; j++)
    ((u16*)&v)[j] = f2b(b2f((u16)x[j]) * b2f((u16)y[j]));
  *(bf16x8*)(feats + (size_t)r * 2816 + c8) = v;
}

// ---------------------------------------------------------------------------
// mgemm256 (8-phase, A-in-LDS / B-in-registers): 256x256 tile, 512 thr
// (8 waves, 2Mx4N), wave tile 128x64, BK=64 as two K-32 slabs. LDS 64KB =
// 4 A-slabs [256][32] u16, swizzled chunk c' = c ^ ((row>>1)&3). B frags
// loaded per-wave from global (BT row-major N x ldb): lane (l16,quad), col
// n0+wn*64+j*16+l16, 8 K-elems at k+quad*8 -- identical frag layout to the
// old LDS path, unswizzled. Per phase: barrier -> [stage A half | WAIT4 +
// load next B slot] -> ds_reads for NEXT phase into alt reg set ->
// sched_barrier(0) -> 16 MFMA. WAIT4 ledger: each awaited slab has exactly
// 4 younger A-gload events (in-order retirement => landed; B loads after it
// only strengthen). C = lrelu(A@B + bias); epilogue zero-fills [N, ldc).
// Requires: Kpad % 128 == 0 (>=256), A rows alloc >= gby*256, BT rows alloc
// >= gridDim.x*256 zero-padded.
// ---------------------------------------------------------------------------
__global__ __launch_bounds__(512, 2) void mgemm256(
    const u16* __restrict__ A, const u16* __restrict__ BT,
    const u16* __restrict__ bias, u16* __restrict__ C, int M, int N, int Kpad,
    int lda, int ldb, int ldc, float slope) {
  // 4 A-slabs of 16KB: slab(p,kk) at (p*2+kk)*8192 u16.
  __shared__ u16 As[32768];
  const int t = threadIdx.x;
  const int lane = t & 63, wave = t >> 6;
  const int quad = lane >> 4, l16 = lane & 15;
  const int wm = wave >> 2, wn = wave & 3;
  const int m0 = blockIdx.y * 256, n0 = blockIdx.x * 256;

  // staging: thread t -> row r0 = t>>2 (and +128 on 2nd gload), LDS chunk
  // c' = t&3; source chunk c = c' ^ ((r0>>1)&3) = (t&3) ^ ((t>>3)&3).
  const int r0 = t >> 2;
  const int csrc = (t & 3) ^ ((t >> 3) & 3);
  const u16* Ap = A + (size_t)(m0 + r0) * lda + csrc * 8;
  const size_t a128 = (size_t)128 * lda;
  const int dst = wave * 512;  // u16 offset of wave's 1KB within a call

  // A reads: row = wm*128 + i*16 + l16; swizzled chunk = quad^((l16>>1)&3)
  const int rsw = (quad ^ ((l16 >> 1) & 3)) * 8;
  const int a_base = (wm * 128 + l16) * 32 + rsw;  // + i*512

  // B global base for this wave's column block
  const u16* Bw = BT + (size_t)(n0 + wn * 64 + l16) * ldb + quad * 8;

  f32x4 zero4 = {0.f, 0.f, 0.f, 0.f};
  f32x4 acc[8][4];
#pragma unroll
  for (int i = 0; i < 8; i++)
#pragma unroll
    for (int j = 0; j < 4; j++) acc[i][j] = zero4;

  const int iters = Kpad >> 7;  // 2 K-64 tiles per iteration

  bf16x8 ra0[4], ra1[4], rb0[4], rb1[4];

#define ST_A(slab, kofs)                              \
  {                                                   \
    u16* d_ = As + (slab) * 8192 + dst;               \
    async_ld16(Ap + (kofs), d_);                      \
    async_ld16(Ap + a128 + (kofs), d_ + 4096);        \
  }
#define LDA4(rr, slab, i0)                                                   \
  _Pragma("unroll") for (int i = 0; i < 4; i++) rr[i] =                      \
      *(const bf16x8*)(As + (slab) * 8192 + a_base + ((i0) + i) * 512);
#define GLB4(rr, kofs)                                                       \
  _Pragma("unroll") for (int j = 0; j < 4; j++) rr[j] =                      \
      *(const bf16x8*)(Bw + (size_t)(j * 16) * ldb + (kofs));
#define BAR __builtin_amdgcn_s_barrier();
#define SBAR __builtin_amdgcn_sched_barrier(0);
#define MFMA16(AS, BS, A0)                                                   \
  _Pragma("unroll") for (int i = 0; i < 4; i++)                              \
      _Pragma("unroll") for (int j = 0; j < 4; j++) acc[(A0) + i][j] =       \
          __builtin_amdgcn_mfma_f32_16x16x32_bf16(AS[i], BS[j],              \
                                                  acc[(A0) + i][j], 0, 0, 0);
#define WAIT4 asm volatile("s_waitcnt vmcnt(4)" ::: "memory");
#define WAIT2 asm volatile("s_waitcnt vmcnt(2)" ::: "memory");
#define WAIT0 asm volatile("s_waitcnt vmcnt(0)" ::: "memory");

  // ---- prologue: A slabs 0,1,2 (T0kk0,T0kk1,T1kk0); B slot T0kk0 ----
  ST_A(0, 0);
  ST_A(1, 32);
  ST_A(2, 64);
  WAIT4;  // slab0: 4 younger A-events -> landed
  BAR;
  GLB4(rb0, 0);
  LDA4(ra0, 0, 0);  // A reads for ph1

  for (int it = 0; it < iters - 1; ++it) {
    const size_t tb = (size_t)it * 128;  // K-elem base of T0=2*it
    // ph1: MFMA T0kk0 lo; read slab0 hi; stage T1.Akk1 -> slab3
    BAR; ST_A(3, tb + 96);                  LDA4(ra1, 0, 4); SBAR; MFMA16(ra0, rb0, 0);
    // ph2: MFMA T0kk0 hi; WAIT slab1; load B T0kk1; read slab1 lo
    BAR; WAIT4; GLB4(rb1, tb + 32);         LDA4(ra0, 1, 0); SBAR; MFMA16(ra1, rb0, 4);
    // ph3: stage T2.Akk0 -> slab0
    BAR; ST_A(0, tb + 128);                 LDA4(ra1, 1, 4); SBAR; MFMA16(ra0, rb1, 0);
    // ph4: WAIT slab2; load B T1kk0
    BAR; WAIT4; GLB4(rb0, tb + 64);         LDA4(ra0, 2, 0); SBAR; MFMA16(ra1, rb1, 4);
    // ph5: stage T2.Akk1 -> slab1
    BAR; ST_A(1, tb + 160);                 LDA4(ra1, 2, 4); SBAR; MFMA16(ra0, rb0, 0);
    // ph6: WAIT slab3; load B T1kk1
    BAR; WAIT4; GLB4(rb1, tb + 96);         LDA4(ra0, 3, 0); SBAR; MFMA16(ra1, rb0, 4);
    // ph7: stage T3.Akk0 -> slab2
    BAR; ST_A(2, tb + 192);                 LDA4(ra1, 3, 4); SBAR; MFMA16(ra0, rb1, 0);
    // ph8: WAIT slab0(next T0kk0); load B next T0kk0
    BAR; WAIT4; GLB4(rb0, tb + 128);        LDA4(ra0, 0, 0); SBAR; MFMA16(ra1, rb1, 4);
  }

  // ---- peeled last iteration: stages only ph1; drains 4 -> 2 -> 0 ----
  {
    const size_t tb = (size_t)(iters - 1) * 128;
    BAR; ST_A(3, tb + 96);                  LDA4(ra1, 0, 4); SBAR; MFMA16(ra0, rb0, 0);
    BAR; WAIT4; GLB4(rb1, tb + 32);         LDA4(ra0, 1, 0); SBAR; MFMA16(ra1, rb0, 4);
    BAR;                                    LDA4(ra1, 1, 4); SBAR; MFMA16(ra0, rb1, 0);
    BAR; WAIT2; GLB4(rb0, tb + 64);         LDA4(ra0, 2, 0); SBAR; MFMA16(ra1, rb1, 4);
    BAR;                                    LDA4(ra1, 2, 4); SBAR; MFMA16(ra0, rb0, 0);
    BAR; WAIT0; GLB4(rb1, tb + 96);         LDA4(ra0, 3, 0); SBAR; MFMA16(ra1, rb0, 4);
    BAR;                                    LDA4(ra1, 3, 4); SBAR; MFMA16(ra0, rb1, 0);
    SBAR; MFMA16(ra1, rb1, 4);
  }
#undef ST_A
#undef LDA4
#undef GLB4
#undef BAR
#undef SBAR
#undef MFMA16
#undef WAIT4
#undef WAIT2
#undef WAIT0

  // ---- epilogue ----
#pragma unroll
  for (int j = 0; j < 4; j++) {
    int col = n0 + wn * 64 + j * 16 + l16;
    if (col >= ldc) continue;
    float bv = 0.f;
    if (bias != nullptr && col < N) bv = b2f(bias[col]);
#pragma unroll
    for (int i = 0; i < 8; i++) {
#pragma unroll
      for (int r = 0; r < 4; r++) {
        int row = m0 + wm * 128 + i * 16 + quad * 4 + r;
        if (row >= M) continue;
        float v;
        if (col < N) {
          v = acc[i][j][r] + bv;
          v = (v > 0.f) ? v : v * slope;
        } else {
          v = 0.f;
        }
        C[(size_t)row * ldc + col] = f2b(v);
      }
    }
  }
}

// ---------------------------------------------------------------------------
// f32 VALU GEMM (front end, bias path; used where grid is already large)
// ---------------------------------------------------------------------------
__global__ __launch_bounds__(256) void vgemm_f(
    const float* __restrict__ A, const float* __restrict__ BT,
    const float* __restrict__ bias, float* __restrict__ C, int M, int N, int K,
    int lda, int ldb, int ldc) {
  __shared__ float As[16 * 66];
  __shared__ float Bs[64 * 66];
  const int t = threadIdx.x;
  const int m0 = blockIdx.y * 16, n0 = blockIdx.x * 64;
  const int tx = t & 63, ty = t >> 6;
  float acc[4] = {0.f, 0.f, 0.f, 0.f};
  for (int k0 = 0; k0 < K; k0 += 64) {
    for (int idx = t; idx < 16 * 64; idx += 256) {
      int r = idx >> 6, k = idx & 63;
      int m = m0 + r, kk = k0 + k;
      As[r * 66 + k] = (m < M && kk < K) ? A[(size_t)m * lda + kk] : 0.f;
    }
    for (int idx = t; idx < 64 * 64; idx += 256) {
      int nr = idx >> 6, k = idx & 63;
      int nn = n0 + nr, kk = k0 + k;
      Bs[nr * 66 + k] = (nn < N && kk < K) ? BT[(size_t)nn * ldb + kk] : 0.f;
    }
    __syncthreads();
#pragma unroll 8
    for (int k = 0; k < 64; k++) {
      float b = Bs[tx * 66 + k];
#pragma unroll
      for (int q = 0; q < 4; q++) acc[q] += As[(ty * 4 + q) * 66 + k] * b;
    }
    __syncthreads();
  }
  int col = n0 + tx;
  if (col >= N) return;
  float bv = (bias != nullptr) ? bias[col] : 0.f;
#pragma unroll
  for (int q = 0; q < 4; q++) {
    int row = m0 + ty * 4 + q;
    if (row < M) C[(size_t)row * ldc + col] = acc[q] + bv;
  }
}

// ---------------------------------------------------------------------------
// K-split f32 GEMM: z-grid over K-chunks, partials atomicAdd'd into
// pre-zeroed C (no bias). Fixes latency-bound small-grid GEMMs (R16).
// ---------------------------------------------------------------------------
__global__ __launch_bounds__(256) void vgemm_ks(
    const float* __restrict__ A, const float* __restrict__ BT,
    float* __restrict__ C, int M, int N, int K, int lda, int ldb, int ldc,
    int kchunk) {
  __shared__ float As[16 * 66];
  __shared__ float Bs[64 * 66];
  const int t = threadIdx.x;
  const int m0 = blockIdx.y * 16, n0 = blockIdx.x * 64;
  const int kbeg = blockIdx.z * kchunk;
  int kend = kbeg + kchunk;
  if (kend > K) kend = K;
  const int tx = t & 63, ty = t >> 6;
  float acc[4] = {0.f, 0.f, 0.f, 0.f};
  for (int k0 = kbeg; k0 < kend; k0 += 64) {
    for (int idx = t; idx < 16 * 64; idx += 256) {
      int r = idx >> 6, k = idx & 63;
      int m = m0 + r, kk = k0 + k;
      As[r * 66 + k] = (m < M && kk < kend) ? A[(size_t)m * lda + kk] : 0.f;
    }
    for (int idx = t; idx < 64 * 64; idx += 256) {
      int nr = idx >> 6, k = idx & 63;
      int nn = n0 + nr, kk = k0 + k;
      Bs[nr * 66 + k] = (nn < N && kk < kend) ? BT[(size_t)nn * ldb + kk] : 0.f;
    }
    __syncthreads();
#pragma unroll 8
    for (int k = 0; k < 64; k++) {
      float b = Bs[tx * 66 + k];
#pragma unroll
      for (int q = 0; q < 4; q++) acc[q] += As[(ty * 4 + q) * 66 + k] * b;
    }
    __syncthreads();
  }
  int col = n0 + tx;
  if (col >= N) return;
#pragma unroll
  for (int q = 0; q < 4; q++) {
    int row = m0 + ty * 4 + q;
    if (row < M) atomicAdd(&C[(size_t)row * ldc + col], acc[q]);
  }
}

__global__ void k_zero2(int* __restrict__ a, int* __restrict__ b, int n) {
  int tid = blockIdx.x * 256 + threadIdx.x;
  if (tid < n) { a[tid] = 0; b[tid] = 0; }
}

__global__ void k_zerof(float* __restrict__ a, int n) {
  int tid = blockIdx.x * 256 + threadIdx.x;
  if (tid < n) a[tid] = 0.f;
}

// ---------------------------------------------------------------------------
// GAT
// ---------------------------------------------------------------------------
__global__ void k_edge_e(const float* __restrict__ xl,
                         const float* __restrict__ xr,
                         const int* __restrict__ ei,
                         const float* __restrict__ att, float* __restrict__ e,
                         int E, int Etot) {
  __shared__ float attf[1024];
  int t = threadIdx.x;
  for (int i = t; i < 1024; i += 256) attf[i] = att[i];
  __syncthreads();
  int lane = t & 63;
  int eid = blockIdx.x * 4 + (t >> 6);
  if (eid >= Etot) return;
  int src = (eid < E) ? ei[eid] : (eid - E);
  int dst = (eid < E) ? ei[E + eid] : (eid - E);
  const float* pl = xl + (size_t)src * 1024;
  const float* pr = xr + (size_t)dst * 1024;
#pragma unroll
  for (int h = 0; h < 8; h++) {
    float a0 = pl[h * 128 + lane] + pr[h * 128 + lane];
    float a1 = pl[h * 128 + 64 + lane] + pr[h * 128 + 64 + lane];
    a0 = (a0 > 0.f) ? a0 : 0.2f * a0;
    a1 = (a1 > 0.f) ? a1 : 0.2f * a1;
    float p = a0 * attf[h * 128 + lane] + a1 * attf[h * 128 + 64 + lane];
#pragma unroll
    for (int off = 32; off; off >>= 1) p += __shfl_xor(p, off);
    if (lane == 0) e[(size_t)eid * 8 + h] = p;
  }
}

__global__ void k_count(const int* __restrict__ ei, int* __restrict__ cnt,
                        int E, int Etot) {
  int tid = blockIdx.x * 256 + threadIdx.x;
  if (tid >= Etot) return;
  int dst = (tid < E) ? ei[E + tid] : (tid - E);
  atomicAdd(&cnt[dst], 1);
}

__global__ void k_scan(const int* __restrict__ cnt, int* __restrict__ rowstart,
                       int Nn) {
  __shared__ int part[257];
  int t = threadIdx.x;
  int chunk = (Nn + 255) / 256;
  int b = t * chunk;
  int en = b + chunk; if (en > Nn) en = Nn;
  int s = 0;
  for (int i = b; i < en; i++) s += cnt[i];
  part[t] = s;
  __syncthreads();
  if (t == 0) {
    int acc = 0;
    for (int i = 0; i < 256; i++) { int v = part[i]; part[i] = acc; acc += v; }
    part[256] = acc;
  }
  __syncthreads();
  int run = part[t];
  for (int i = b; i < en; i++) { rowstart[i] = run; run += cnt[i]; }
  if (t == 0) rowstart[Nn] = part[256];
}

__global__ void k_scatter(const int* __restrict__ ei,
                          const int* __restrict__ rowstart,
                          int* __restrict__ cur, int* __restrict__ csr, int E,
                          int Etot) {
  int tid = blockIdx.x * 256 + threadIdx.x;
  if (tid >= Etot) return;
  int dst = (tid < E) ? ei[E + tid] : (tid - E);
  int p = atomicAdd(&cur[dst], 1);
  unsigned idx = (unsigned)(rowstart[dst] + p);
  if (idx < (unsigned)Etot) csr[idx] = tid;
}

__global__ void k_softmax(const float* __restrict__ e,
                          const int* __restrict__ csr,
                          const int* __restrict__ rowstart,
                          float* __restrict__ wgt, int Nn, int Etot) {
  int t = threadIdx.x;
  int lane = t & 63;
  int d = blockIdx.x * 4 + (t >> 6);
  if (d >= Nn) return;
  int rs = rowstart[d], re = rowstart[d + 1];
  for (int h = 0; h < 8; h++) {
    float mx = -3.0e38f;
    for (int i = rs + lane; i < re; i += 64) {
      unsigned eid = (unsigned)csr[i];
      if (eid < (unsigned)Etot) mx = fmaxf(mx, e[(size_t)eid * 8 + h]);
    }
#pragma unroll
    for (int off = 32; off; off >>= 1) mx = fmaxf(mx, __shfl_xor(mx, off));
    if (mx < -1.0e37f) mx = 0.f;
    float s = 0.f;
    for (int i = rs + lane; i < re; i += 64) {
      unsigned eid = (unsigned)csr[i];
      if (eid < (unsigned)Etot) s += expf(e[(size_t)eid * 8 + h] - mx);
    }
#pragma unroll
    for (int off = 32; off; off >>= 1) s += __shfl_xor(s, off);
    float inv = (s > 0.f) ? 1.f / s : 0.f;
    for (int i = rs + lane; i < re; i += 64) {
      unsigned eid = (unsigned)csr[i];
      if (eid < (unsigned)Etot)
        wgt[(size_t)eid * 8 + h] = expf(e[(size_t)eid * 8 + h] - mx) * inv;
    }
  }
}

__global__ void k_aggregate(const float* __restrict__ wgt,
                            const float* __restrict__ xl,
                            const int* __restrict__ ei,
                            const int* __restrict__ csr,
                            const int* __restrict__ rowstart,
                            const float* __restrict__ gbias,
                            float* __restrict__ res, int E, int Etot) {
  int d = blockIdx.x;
  int t = threadIdx.x;
  int c = t & 127, hb = t >> 7;
  int rs = rowstart[d], re = rowstart[d + 1];
  float acc[4] = {0.f, 0.f, 0.f, 0.f};
  for (int i = rs; i < re; i++) {
    unsigned eid = (unsigned)csr[i];
    if (eid >= (unsigned)Etot) continue;
    int src = (eid < (unsigned)E) ? ei[eid] : (int)(eid - E);
    const float* px = xl + (size_t)src * 1024 + hb * 512 + c;
    const float* pw = wgt + (size_t)eid * 8 + hb * 4;
#pragma unroll
    for (int q = 0; q < 4; q++) acc[q] += pw[q] * px[q * 128];
  }
#pragma unroll
  for (int q = 0; q < 4; q++) {
    int idx = (hb * 4 + q) * 128 + c;
    res[(size_t)d * 1024 + idx] = acc[q] + gbias[idx];
  }
}

// ---------------------------------------------------------------------------
// CNN: f32 in, f32 out to d_out (stride 2778), bf16 emb (stride 2784, padded)
// ---------------------------------------------------------------------------
__global__ void k_cnn(const float* __restrict__ res,
                      const float* __restrict__ cw1, const float* __restrict__ cb1,
                      const float* __restrict__ cw4, const float* __restrict__ cb4,
                      const float* __restrict__ cw16, const float* __restrict__ cb16,
                      const float* __restrict__ cw32, const float* __restrict__ cb32,
                      float* __restrict__ outc, u16* __restrict__ emb) {
  __shared__ float xs[1024];
  __shared__ float wc[2544];
  __shared__ float cb[24];
  int t = threadIdx.x, node = blockIdx.x;
  for (int i = t; i < 1024; i += 256) xs[i] = res[(size_t)node * 1024 + i];
  for (int i = t; i < 48; i += 256) wc[i] = cw1[i];
  for (int i = t; i < 192; i += 256) wc[48 + i] = cw4[i];
  for (int i = t; i < 768; i += 256) wc[240 + i] = cw16[i];
  for (int i = t; i < 1536; i += 256) wc[1008 + i] = cw32[i];
  if (t < 6) {
    cb[t] = cb1[t];
    cb[6 + t] = cb4[t];
    cb[12 + t] = cb16[t];
    cb[18 + t] = cb32[t];
  }
  __syncthreads();
  for (int o = t; o < 2778; o += 256) {
    int k, W, base, boff, rr;
    if (o < 768)       { k = 1;  W = 128; base = 0;    boff = 0;  rr = o; }
    else if (o < 1518) { k = 4;  W = 125; base = 48;   boff = 6;  rr = o - 768; }
    else if (o < 2196) { k = 16; W = 113; base = 240;  boff = 12; rr = o - 1518; }
    else               { k = 32; W = 97;  base = 1008; boff = 18; rr = o - 2196; }
    int oc = rr / W, wp = rr - oc * W;
    const float* wgt = &wc[base + oc * 8 * k];
    float v = cb[boff + oc];
    for (int h = 0; h < 8; h++)
      for (int j = 0; j < k; j++) v += xs[h * 128 + wp + j] * wgt[h * k + j];
    v = fmaxf(v, 0.f);
    outc[(size_t)node * 2778 + o] = v;
    emb[(size_t)node * 2784 + o] = f2b(v);
  }
  if (t < 6) emb[(size_t)node * 2784 + 2778 + t] = 0;  // zero K-pad
}

// ---------------------------------------------------------------------------
__global__ void k_gemv_sig(const u16* __restrict__ hh3,
                           const u16* __restrict__ w4, float* __restrict__ pred,
                           int M, int K, int ldk) {
  __shared__ float ws[464];
  int t = threadIdx.x;
  for (int i = t; i < K; i += 256) ws[i] = b2f(w4[i]);
  __syncthreads();
  int lane = t & 63;
  int m = blockIdx.x * 4 + (t >> 6);
  if (m >= M) return;
  const u16* p = hh3 + (size_t)m * ldk;
  float s = 0.f;
  for (int i = lane; i < K; i += 64) s += b2f(p[i]) * ws[i];
#pragma unroll
  for (int off = 32; off; off >>= 1) s += __shfl_xor(s, off);
  if (!(s == s)) s = 0.f;
  s = fminf(fmaxf(s, -30.f), 30.f);
  if (lane == 0) pred[m] = 1.f / (1.f + expf(-s));
}

__global__ void k_labels(float* __restrict__ lab, int P) {
  int tid = blockIdx.x * 256 + threadIdx.x;
  if (tid < 2 * P) lab[tid] = (tid < P) ? 1.f : 0.f;
}

__global__ void k_sentinel(float* __restrict__ pred, int M, float val) {
  int tid = blockIdx.x * 256 + threadIdx.x;
  if (tid < M) pred[tid] = val;
}

// ---------------------------------------------------------------------------
extern "C" void kernel_launch(void* const* d_in, const int* in_sizes, int n_in,
                              void* d_out, int out_size, void* d_ws,
                              size_t ws_size, hipStream_t stream) {
  (void)in_sizes; (void)n_in; (void)out_size;
  const int* ei = (const int*)d_in[2];
  const int* posp = (const int*)d_in[3];
  const int* negp = (const int*)d_in[4];

  const int E = 80000, ET = 82300, P = 40000, M = 80000;

  float* outp = (float*)d_out;
  float* outl = outp + 80000;
  float* outc = outp + 160000;

  k_labels<<<(2 * P + 255) / 256, 256, 0, stream>>>(outl, P);

  char* base = (char*)d_ws;
  size_t off = 0;
  auto alloc = [&](size_t bytes) -> void* {
    void* p = base + off;
    off = (off + bytes + 255) & ~(size_t)255;
    return p;
  };
  // front-end f32 copies
  float* mic_f = (float*)alloc((size_t)1500 * 1500 * 4);
  float* dis_f = (float*)alloc((size_t)800 * 800 * 4);
  float* WmT_f = (float*)alloc((size_t)128 * 1500 * 4);
  float* WdT_f = (float*)alloc((size_t)128 * 800 * 4);
  float* WlT_f = (float*)alloc((size_t)1024 * 128 * 4);
  float* WrT_f = (float*)alloc((size_t)1024 * 128 * 4);
  float* bl_f = (float*)alloc(1024 * 4);
  float* br_f = (float*)alloc(1024 * 4);
  float* att_f = (float*)alloc(1024 * 4);
  float* gbias_f = (float*)alloc(1024 * 4);
  float* cw1_f = (float*)alloc(48 * 4);
  float* cb1_f = (float*)alloc(6 * 4);
  float* cw4_f = (float*)alloc(192 * 4);
  float* cb4_f = (float*)alloc(6 * 4);
  float* cw16_f = (float*)alloc(768 * 4);
  float* cb16_f = (float*)alloc(6 * 4);
  float* cw32_f = (float*)alloc(1536 * 4);
  float* cb32_f = (float*)alloc(6 * 4);
  // MLP bf16 weights: rows padded to 256-mult, K padded to 64-mult (even
  // tile count: 2816/1408/768), zero-filled
  u16* m1T = (u16*)alloc((size_t)1536 * 2816 * 2);  // N 1389->1536, K->2816
  u16* m2T = (u16*)alloc((size_t)768 * 1408 * 2);   // N 694->768,  K->1408
  u16* m3T = (u16*)alloc((size_t)512 * 768 * 2);    // N 463->512,  K->768
  u16* mb1_b = (u16*)alloc(1389 * 2);
  u16* mb2_b = (u16*)alloc(694 * 2);
  u16* mb3_b = (u16*)alloc(463 * 2);
  u16* mw4_b = (u16*)alloc(463 * 2);
  // intermediates
  float* hbuf = (float*)alloc((size_t)2300 * 128 * 4);
  float* xlf = (float*)alloc((size_t)2300 * 1024 * 4);
  float* xrf = (float*)alloc((size_t)2300 * 1024 * 4);
  float* resf = xrf;  // xr dead after k_edge_e
  float* ebuf = (float*)alloc((size_t)ET * 8 * 4);
  float* wbuf = (float*)alloc((size_t)ET * 8 * 4);
  u16* emb = (u16*)alloc((size_t)2300 * 2784 * 2);
  int* cnt = (int*)alloc(2300 * 4);
  int* rowst = (int*)alloc(2304 * 4);
  int* cur = (int*)alloc(2300 * 4);
  int* csr = (int*)alloc((size_t)ET * 4);
  size_t fixed_end = off;

  // chunk: feats (R x 2816) + hh1 (R x 1408); hh2 ALIASES feats (feats is
  // dead after L1; L2 writes hh2 after L1 reads feats). R multiple of 256.
  const size_t per_row = (size_t)(2816 + 1408) * 2;
  size_t avail = (ws_size > fixed_end) ? (ws_size - fixed_end) : 0;
  long long Rll = (long long)(avail / per_row);
  int R = (Rll > M) ? M : (int)Rll;
  R &= ~255;
  if (R > 21760) R = 21760;  // keep feats chunk L3-fittable
  if (fixed_end > ws_size || R < 256) {
    k_sentinel<<<(M + 255) / 256, 256, 0, stream>>>(outp, M, 0.25f);
    return;
  }
  u16* feats = (u16*)(base + fixed_end);
  u16* hh1 = feats + (size_t)R * 2816;
  u16* hh2 = feats;  // alias: L2 output overwrites dead feats

  k_zero2<<<(2300 + 255) / 256, 256, 0, stream>>>(cnt, cur, 2300);
  k_zerof<<<(2300 * 128 + 255) / 256, 256, 0, stream>>>(hbuf, 2300 * 128);

  // ---- canonicalize inputs ----
  cvt_f<<<(2250000 + 255) / 256, 256, 0, stream>>>(d_in[0], mic_f, 2250000);
  cvt_f<<<(640000 + 255) / 256, 256, 0, stream>>>(d_in[1], dis_f, 640000);
  cvt_f_t<<<(192000 + 255) / 256, 256, 0, stream>>>(d_in[6], WmT_f, 1500, 128);
  cvt_f_t<<<(102400 + 255) / 256, 256, 0, stream>>>(d_in[7], WdT_f, 800, 128);
  cvt_f_t<<<(131072 + 255) / 256, 256, 0, stream>>>(d_in[8], WlT_f, 128, 1024);
  cvt_f<<<4, 256, 0, stream>>>(d_in[9], bl_f, 1024);
  cvt_f_t<<<(131072 + 255) / 256, 256, 0, stream>>>(d_in[10], WrT_f, 128, 1024);
  cvt_f<<<4, 256, 0, stream>>>(d_in[11], br_f, 1024);
  cvt_f<<<4, 256, 0, stream>>>(d_in[12], att_f, 1024);
  cvt_f<<<4, 256, 0, stream>>>(d_in[13], gbias_f, 1024);
  cvt_f<<<1, 256, 0, stream>>>(d_in[14], cw1_f, 48);
  cvt_f<<<1, 256, 0, stream>>>(d_in[15], cb1_f, 6);
  cvt_f<<<1, 256, 0, stream>>>(d_in[16], cw4_f, 192);
  cvt_f<<<1, 256, 0, stream>>>(d_in[17], cb4_f, 6);
  cvt_f<<<3, 256, 0, stream>>>(d_in[18], cw16_f, 768);
  cvt_f<<<1, 256, 0, stream>>>(d_in[19], cb16_f, 6);
  cvt_f<<<6, 256, 0, stream>>>(d_in[20], cw32_f, 1536);
  cvt_f<<<1, 256, 0, stream>>>(d_in[21], cb32_f, 6);
  cvt_b_tt<<<dim3(88, 48), 256, 0, stream>>>(d_in[22], m1T, 2778, 1389, 2816,
                                             1536);
  cvt_b<<<(1389 + 255) / 256, 256, 0, stream>>>(d_in[23], mb1_b, 1389);
  cvt_b_tt<<<dim3(44, 24), 256, 0, stream>>>(d_in[24], m2T, 1389, 694, 1408,
                                             768);
  cvt_b<<<(694 + 255) / 256, 256, 0, stream>>>(d_in[25], mb2_b, 694);
  cvt_b_tt<<<dim3(24, 16), 256, 0, stream>>>(d_in[26], m3T, 694, 463, 768, 512);
  cvt_b<<<(463 + 255) / 256, 256, 0, stream>>>(d_in[27], mb3_b, 463);
  cvt_b<<<(463 + 255) / 256, 256, 0, stream>>>(d_in[28], mw4_b, 463);

  // ---- front end ----
  // mic/dis: K-split (chunk 192) into pre-zeroed hbuf via atomicAdd
  vgemm_ks<<<dim3(2, 94, 8), 256, 0, stream>>>(mic_f, WmT_f, hbuf, 1500, 128,
                                               1500, 1500, 1500, 128, 192);
  vgemm_ks<<<dim3(2, 50, 5), 256, 0, stream>>>(dis_f, WdT_f,
                                               hbuf + (size_t)1500 * 128, 800,
                                               128, 800, 800, 800, 128, 192);
  vgemm_f<<<dim3(16, 144), 256, 0, stream>>>(hbuf, WlT_f, bl_f, xlf, 2300,
                                             1024, 128, 128, 128, 1024);
  vgemm_f<<<dim3(16, 144), 256, 0, stream>>>(hbuf, WrT_f, br_f, xrf, 2300,
                                             1024, 128, 128, 128, 1024);

  k_edge_e<<<(ET + 3) / 4, 256, 0, stream>>>(xlf, xrf, ei, att_f, ebuf, E, ET);
  k_count<<<(ET + 255) / 256, 256, 0, stream>>>(ei, cnt, E, ET);
  k_scan<<<1, 256, 0, stream>>>(cnt, rowst, 2300);
  k_scatter<<<(ET + 255) / 256, 256, 0, stream>>>(ei, rowst, cur, csr, E, ET);
  k_softmax<<<(2300 + 3) / 4, 256, 0, stream>>>(ebuf, csr, rowst, wbuf, 2300, ET);
  k_aggregate<<<2300, 256, 0, stream>>>(wbuf, xlf, ei, csr, rowst, gbias_f,
                                        resf, E, ET);

  k_cnn<<<2300, 256, 0, stream>>>(resf, cw1_f, cb1_f, cw4_f, cb4_f, cw16_f,
                                  cb16_f, cw32_f, cb32_f, outc, emb);

  // ---- MLP: feats precompute + 8-phase 256-tile MFMA GEMMs, chunked ----
  for (int c0 = 0; c0 < M; c0 += R) {
    int rows = (M - c0 < R) ? (M - c0) : R;
    int gby = (rows + 255) / 256;
    k_feats<<<((size_t)rows * 352 + 255) / 256, 256, 0, stream>>>(
        emb, posp, negp, P, c0, rows, feats);
    mgemm256<<<dim3(6, gby), 512, 0, stream>>>(feats, m1T, mb1_b, hh1, rows,
                                               1389, 2816, 2816, 2816, 1408,
                                               0.01f);
    mgemm256<<<dim3(3, gby), 512, 0, stream>>>(hh1, m2T, mb2_b, hh2, rows, 694,
                                               1408, 1408, 1408, 768, 0.01f);
    mgemm256<<<dim3(2, gby), 512, 0, stream>>>(hh2, m3T, mb3_b, hh1, rows, 463,
                                               768, 768, 768, 480, 0.01f);
    k_gemv_sig<<<(rows + 3) / 4, 256, 0, stream>>>(hh1, mw4_b, outp + c0, rows,
                                                   463, 480);
  }
}

// Round 11
// 1993.731 us; speedup vs baseline: 1.2598x; 1.2598x over previous
//
#include <hip/hip_runtime.h>

// ===========================================================================
// GAT_CNN_DASE :: gfx950 :: R21 (consolidation).
// R20 post-mortem: B-reg streaming FALSIFIED (310us, MfmaUtil 25%) -- B's
// scattered L2 loads sit one barrier from their MFMA and every vmcnt wait
// drains them. Reverted.
// Model that fits R13..R20: wall/iter = MFMA + LDS-read cycles, SUMMED.
// R18 (256^2, 8-phase, 1-barrier, reg read-ahead, no setprio) = 168us L1 is
// ~6% above that structural floor; all intra-structure levers A/B'd null.
// R21 = R18 mgemm256 verbatim + two host-side wins decoupled from the R19
// regression: (1) hh2 aliases feats (dead after L1; per-chunk sequence
// feats->L1->hh1, hh1->L2->hh2(=feats), hh2->L3->hh1, gemv(hh1) verified);
// (2) per_row 9984->8448 -> R = 21760 cap -> 4 chunks instead of 5.
// ===========================================================================

typedef unsigned short u16;
typedef __attribute__((ext_vector_type(8))) short bf16x8;
typedef __attribute__((ext_vector_type(4))) float f32x4;

__device__ __forceinline__ float b2f(u16 u) {
  unsigned v = ((unsigned)u) << 16;
  return __builtin_bit_cast(float, v);
}
__device__ __forceinline__ u16 f2b(float f) {
  unsigned x = __builtin_bit_cast(unsigned, f);
  x += 0x7fffu + ((x >> 16) & 1u);
  return (u16)(x >> 16);
}

// async global->LDS, 16B per lane; LDS dest = wave-uniform base + lane*16
__device__ __forceinline__ void async_ld16(const u16* g, u16* l) {
  __builtin_amdgcn_global_load_lds(
      (const __attribute__((address_space(1))) void*)g,
      (__attribute__((address_space(3))) void*)l, 16, 0, 0);
}

// bf16 data: ~100% of u16s have exponent in [100,140]; f32-as-u16: ~58%.
__device__ __forceinline__ int sniff_bf16(const void* p, int n) {
  const u16* pu = (const u16*)p;
  int ns = n < 128 ? n : 128;
  int sane = 0, nz = 0;
  for (int i = 0; i < ns; i++) {
    u16 v = pu[i];
    if (v) nz++;
    int e = (v >> 7) & 0xFF;
    if (e >= 100 && e <= 140) sane++;
  }
  return (nz == 0) || (sane * 8 >= ns * 7);
}
__device__ __forceinline__ float ld_any(const void* p, size_t i, int isbf) {
  return isbf ? b2f(((const u16*)p)[i]) : ((const float*)p)[i];
}

__global__ void cvt_f(const void* __restrict__ in, float* __restrict__ out,
                      int n) {
  __shared__ int sbf;
  if (threadIdx.x == 0) sbf = sniff_bf16(in, n);
  __syncthreads();
  int tid = blockIdx.x * 256 + threadIdx.x;
  if (tid < n) out[tid] = ld_any(in, tid, sbf);
}
// in[k*N+n] -> out[n*K+k] (small front-end weights)
__global__ void cvt_f_t(const void* __restrict__ in, float* __restrict__ out,
                        int K, int N) {
  __shared__ int sbf;
  if (threadIdx.x == 0) sbf = sniff_bf16(in, K * N);
  __syncthreads();
  int tid = blockIdx.x * 256 + threadIdx.x;
  if (tid >= K * N) return;
  int nn = tid / K, k = tid - nn * K;
  out[tid] = ld_any(in, (size_t)k * N + nn, sbf);
}
__global__ void cvt_b(const void* __restrict__ in, u16* __restrict__ out,
                      int n) {
  __shared__ int sbf;
  if (threadIdx.x == 0) sbf = sniff_bf16(in, n);
  __syncthreads();
  int tid = blockIdx.x * 256 + threadIdx.x;
  if (tid < n) out[tid] = f2b(ld_any(in, tid, sbf));
}
// tiled transpose-convert: in K x N -> out Npad x Kpad bf16, zero-padded.
__global__ void cvt_b_tt(const void* __restrict__ in, u16* __restrict__ out,
                         int K, int N, int Kpad, int Npad) {
  __shared__ int sbf;
  __shared__ float tile[32][33];
  if (threadIdx.x == 0) sbf = sniff_bf16(in, K * N);
  __syncthreads();
  int k0 = blockIdx.x * 32, n0 = blockIdx.y * 32;
  int tx = threadIdx.x & 31, ty = threadIdx.x >> 5;  // 32x8
#pragma unroll
  for (int i = 0; i < 32; i += 8) {
    int k = k0 + ty + i, n = n0 + tx;
    tile[ty + i][tx] =
        (k < K && n < N) ? ld_any(in, (size_t)k * N + n, sbf) : 0.f;
  }
  __syncthreads();
#pragma unroll
  for (int i = 0; i < 32; i += 8) {
    int n = n0 + ty + i, k = k0 + tx;
    if (n < Npad && k < Kpad) out[(size_t)n * Kpad + k] = f2b(tile[tx][ty + i]);
  }
}

// ---------------------------------------------------------------------------
// feats chunk: feats[r][0..2784) = emb[p0[..]] * emb[1500+p1[..]], cols
// 2784..2816 zeroed (K padded to 2816 for BK=64). One thread per 8 elems.
// ---------------------------------------------------------------------------
__global__ void k_feats(const u16* __restrict__ emb,
                        const int* __restrict__ posp,
                        const int* __restrict__ negp, int npos, int mbase,
                        int rows, u16* __restrict__ feats) {
  int idx = blockIdx.x * 256 + threadIdx.x;
  int r = idx / 352, c8 = (idx - r * 352) * 8;
  if (r >= rows) return;
  if (c8 >= 2784) {
    bf16x8 z = {0, 0, 0, 0, 0, 0, 0, 0};
    *(bf16x8*)(feats + (size_t)r * 2816 + c8) = z;
    return;
  }
  int g = mbase + r;
  const int* pp = (g < npos) ? (posp + 2 * g) : (negp + 2 * (g - npos));
  bf16x8 x = *(const bf16x8*)(emb + (size_t)pp[0] * 2784 + c8);
  bf16x8 y = *(const bf16x8*)(emb + (size_t)(1500 + pp[1]) * 2784 + c8);
  bf16x8 v;
#pragma unroll
  for (int j = 0; j < 8; j++)
    ((u16*)&v)[j] = f2b(b2f((u16)x[j]) * b2f((u16)y[j]));
  *(bf16x8*)(feats + (size_t)r * 2816 + c8) = v;
}

// ---------------------------------------------------------------------------
// mgemm256 (8-phase, 1 barrier/phase, reg double-buffer, no setprio) -- the
// R18 best-known kernel. 256x256 tile, 512 thr (8 waves, 2Mx4N), wave tile
// 128x64, BK=64 as two K-32 slabs. LDS slabs [256][32] u16, swizzled chunk
// c' = c ^ ((row>>1)&3). Per phase: barrier -> stage -> [vmcnt(6) even] ->
// ds_reads for NEXT phase into alternate reg set -> sched_barrier(0) ->
// 16 MFMA on current set. C = lrelu(A@B + bias); zero-fills cols [N, ldc).
// Requires: Kpad % 128 == 0 (>=256), A rows alloc >= gby*256, BT rows alloc
// >= gridDim.x*256 zero-padded.
// ---------------------------------------------------------------------------
__global__ __launch_bounds__(512, 2) void mgemm256(
    const u16* __restrict__ A, const u16* __restrict__ BT,
    const u16* __restrict__ bias, u16* __restrict__ C, int M, int N, int Kpad,
    int lda, int ldb, int ldc, float slope) {
  // 8 slabs of 16KB: A(p,kk) at (p*2+kk)*8192 u16; B same at +32768.
  __shared__ u16 lds[65536];
  u16* As = lds;
  u16* Bs = lds + 32768;
  const int t = threadIdx.x;
  const int lane = t & 63, wave = t >> 6;
  const int quad = lane >> 4, l16 = lane & 15;
  const int wm = wave >> 2, wn = wave & 3;
  const int m0 = blockIdx.y * 256, n0 = blockIdx.x * 256;

  // staging: thread t -> row r0 = t>>2 (and +128 on 2nd call), LDS 16B-chunk
  // c' = t&3; source chunk c = c' ^ ((r0>>1)&3) = (t&3) ^ ((t>>3)&3).
  const int r0 = t >> 2;
  const int csrc = (t & 3) ^ ((t >> 3) & 3);
  const u16* Ap = A + (size_t)(m0 + r0) * lda + csrc * 8;
  const u16* Bp = BT + (size_t)(n0 + r0) * ldb + csrc * 8;
  const size_t a128 = (size_t)128 * lda, b128 = (size_t)128 * ldb;
  const int dst = wave * 512;  // u16 offset of wave's 1KB within a call

  // reads: row = (wm*128|wn*64) + i*16 + l16; swizzled chunk = quad^((l16>>1)&3)
  const int rsw = (quad ^ ((l16 >> 1) & 3)) * 8;
  const int a_base = (wm * 128 + l16) * 32 + rsw;  // + i*512
  const int b_base = (wn * 64 + l16) * 32 + rsw;   // + j*512

  f32x4 zero4 = {0.f, 0.f, 0.f, 0.f};
  f32x4 acc[8][4];
#pragma unroll
  for (int i = 0; i < 8; i++)
#pragma unroll
    for (int j = 0; j < 4; j++) acc[i][j] = zero4;

  const int iters = Kpad >> 7;  // 2 K-64 tiles per iteration

  bf16x8 ra0[4], ra1[4], rb0[4], rb1[4];

#define ST_A(slab, kofs)                              \
  {                                                   \
    u16* d_ = As + (slab) * 8192 + dst;               \
    async_ld16(Ap + (kofs), d_);                      \
    async_ld16(Ap + a128 + (kofs), d_ + 4096);        \
  }
#define ST_B(slab, kofs)                              \
  {                                                   \
    u16* d_ = Bs + (slab) * 8192 + dst;               \
    async_ld16(Bp + (kofs), d_);                      \
    async_ld16(Bp + b128 + (kofs), d_ + 4096);        \
  }
#define LDA4(rr, slab, i0)                                                   \
  _Pragma("unroll") for (int i = 0; i < 4; i++) rr[i] =                      \
      *(const bf16x8*)(As + (slab) * 8192 + a_base + ((i0) + i) * 512);
#define LDB4(rr, slab)                                                       \
  _Pragma("unroll") for (int j = 0; j < 4; j++) rr[j] =                      \
      *(const bf16x8*)(Bs + (slab) * 8192 + b_base + j * 512);
#define BAR __builtin_amdgcn_s_barrier();
#define SBAR __builtin_amdgcn_sched_barrier(0);
#define MFMA16(AS, BS, A0)                                                   \
  _Pragma("unroll") for (int i = 0; i < 4; i++)                              \
      _Pragma("unroll") for (int j = 0; j < 4; j++) acc[(A0) + i][j] =       \
          __builtin_amdgcn_mfma_f32_16x16x32_bf16(AS[i], BS[j],              \
                                                  acc[(A0) + i][j], 0, 0, 0);
#define WAIT6 asm volatile("s_waitcnt vmcnt(6)" ::: "memory");

  // ---- prologue: 6 halves: t0.Ak0,t0.Bk0,t0.Ak1,t0.Bk1,t1.Ak0,t1.Bk0 ----
  ST_A(0, 0);  ST_B(0, 0);
  ST_A(1, 32); ST_B(1, 32);
  ST_A(2, 64); ST_B(2, 64);
  asm volatile("s_waitcnt vmcnt(6)" ::: "memory");  // t0.Ak0/Bk0/Ak1 landed
  BAR;
  LDA4(ra0, 0, 0); LDB4(rb0, 0);  // reads for ph1

  for (int it = 0; it < iters - 1; ++it) {
    const size_t tb = (size_t)it * 128;  // K-elem base of T0=2*it
    // ph1: MFMA T0kk0 lo; reads ph2 (slab0 hi); stage T1.Ak1
    BAR; ST_A(3, tb + 96);          LDA4(ra1, 0, 4);               SBAR; MFMA16(ra0, rb0, 0);
    // ph2: MFMA T0kk0 hi; reads ph3 (slab1); stage T1.Bk1
    BAR; ST_B(3, tb + 96);  WAIT6;  LDA4(ra0, 1, 0); LDB4(rb1, 1); SBAR; MFMA16(ra1, rb0, 4);
    // ph3
    BAR; ST_A(0, tb + 128);         LDA4(ra1, 1, 4);               SBAR; MFMA16(ra0, rb1, 0);
    // ph4
    BAR; ST_B(0, tb + 128); WAIT6;  LDA4(ra0, 2, 0); LDB4(rb0, 2); SBAR; MFMA16(ra1, rb1, 4);
    // ph5
    BAR; ST_A(1, tb + 160);         LDA4(ra1, 2, 4);               SBAR; MFMA16(ra0, rb0, 0);
    // ph6
    BAR; ST_B(1, tb + 160); WAIT6;  LDA4(ra0, 3, 0); LDB4(rb1, 3); SBAR; MFMA16(ra1, rb0, 4);
    // ph7
    BAR; ST_A(2, tb + 192);         LDA4(ra1, 3, 4);               SBAR; MFMA16(ra0, rb1, 0);
    // ph8: reads next-iter ph1 (slab0 = T2.kk0, landed per ledger)
    BAR; ST_B(2, tb + 192); WAIT6;  LDA4(ra0, 0, 0); LDB4(rb0, 0); SBAR; MFMA16(ra1, rb1, 4);
  }

  // ---- peeled last iteration: stages only ph1/ph2, drain 8 -> 4 -> 0 ----
  {
    const size_t tb = (size_t)(iters - 1) * 128;
    BAR; ST_A(3, tb + 96);          LDA4(ra1, 0, 4);               SBAR; MFMA16(ra0, rb0, 0);
    BAR; ST_B(3, tb + 96);
    asm volatile("s_waitcnt vmcnt(8)" ::: "memory");
    LDA4(ra0, 1, 0); LDB4(rb1, 1);                                 SBAR; MFMA16(ra1, rb0, 4);
    BAR;                            LDA4(ra1, 1, 4);               SBAR; MFMA16(ra0, rb1, 0);
    BAR;
    asm volatile("s_waitcnt vmcnt(4)" ::: "memory");
    LDA4(ra0, 2, 0); LDB4(rb0, 2);                                 SBAR; MFMA16(ra1, rb1, 4);
    BAR;                            LDA4(ra1, 2, 4);               SBAR; MFMA16(ra0, rb0, 0);
    BAR;
    asm volatile("s_waitcnt vmcnt(0)" ::: "memory");
    LDA4(ra0, 3, 0); LDB4(rb1, 3);                                 SBAR; MFMA16(ra1, rb0, 4);
    BAR;                            LDA4(ra1, 3, 4);               SBAR; MFMA16(ra0, rb1, 0);
    BAR;                                                           SBAR; MFMA16(ra1, rb1, 4);
  }
#undef ST_A
#undef ST_B
#undef LDA4
#undef LDB4
#undef BAR
#undef SBAR
#undef MFMA16
#undef WAIT6

  // ---- epilogue ----
#pragma unroll
  for (int j = 0; j < 4; j++) {
    int col = n0 + wn * 64 + j * 16 + l16;
    if (col >= ldc) continue;
    float bv = 0.f;
    if (bias != nullptr && col < N) bv = b2f(bias[col]);
#pragma unroll
    for (int i = 0; i < 8; i++) {
#pragma unroll
      for (int r = 0; r < 4; r++) {
        int row = m0 + wm * 128 + i * 16 + quad * 4 + r;
        if (row >= M) continue;
        float v;
        if (col < N) {
          v = acc[i][j][r] + bv;
          v = (v > 0.f) ? v : v * slope;
        } else {
          v = 0.f;
        }
        C[(size_t)row * ldc + col] = f2b(v);
      }
    }
  }
}

// ---------------------------------------------------------------------------
// f32 VALU GEMM (front end, bias path; used where grid is already large)
// ---------------------------------------------------------------------------
__global__ __launch_bounds__(256) void vgemm_f(
    const float* __restrict__ A, const float* __restrict__ BT,
    const float* __restrict__ bias, float* __restrict__ C, int M, int N, int K,
    int lda, int ldb, int ldc) {
  __shared__ float As[16 * 66];
  __shared__ float Bs[64 * 66];
  const int t = threadIdx.x;
  const int m0 = blockIdx.y * 16, n0 = blockIdx.x * 64;
  const int tx = t & 63, ty = t >> 6;
  float acc[4] = {0.f, 0.f, 0.f, 0.f};
  for (int k0 = 0; k0 < K; k0 += 64) {
    for (int idx = t; idx < 16 * 64; idx += 256) {
      int r = idx >> 6, k = idx & 63;
      int m = m0 + r, kk = k0 + k;
      As[r * 66 + k] = (m < M && kk < K) ? A[(size_t)m * lda + kk] : 0.f;
    }
    for (int idx = t; idx < 64 * 64; idx += 256) {
      int nr = idx >> 6, k = idx & 63;
      int nn = n0 + nr, kk = k0 + k;
      Bs[nr * 66 + k] = (nn < N && kk < K) ? BT[(size_t)nn * ldb + kk] : 0.f;
    }
    __syncthreads();
#pragma unroll 8
    for (int k = 0; k < 64; k++) {
      float b = Bs[tx * 66 + k];
#pragma unroll
      for (int q = 0; q < 4; q++) acc[q] += As[(ty * 4 + q) * 66 + k] * b;
    }
    __syncthreads();
  }
  int col = n0 + tx;
  if (col >= N) return;
  float bv = (bias != nullptr) ? bias[col] : 0.f;
#pragma unroll
  for (int q = 0; q < 4; q++) {
    int row = m0 + ty * 4 + q;
    if (row < M) C[(size_t)row * ldc + col] = acc[q] + bv;
  }
}

// ---------------------------------------------------------------------------
// K-split f32 GEMM: z-grid over K-chunks, partials atomicAdd'd into
// pre-zeroed C (no bias). Fixes latency-bound small-grid GEMMs (R16).
// ---------------------------------------------------------------------------
__global__ __launch_bounds__(256) void vgemm_ks(
    const float* __restrict__ A, const float* __restrict__ BT,
    float* __restrict__ C, int M, int N, int K, int lda, int ldb, int ldc,
    int kchunk) {
  __shared__ float As[16 * 66];
  __shared__ float Bs[64 * 66];
  const int t = threadIdx.x;
  const int m0 = blockIdx.y * 16, n0 = blockIdx.x * 64;
  const int kbeg = blockIdx.z * kchunk;
  int kend = kbeg + kchunk;
  if (kend > K) kend = K;
  const int tx = t & 63, ty = t >> 6;
  float acc[4] = {0.f, 0.f, 0.f, 0.f};
  for (int k0 = kbeg; k0 < kend; k0 += 64) {
    for (int idx = t; idx < 16 * 64; idx += 256) {
      int r = idx >> 6, k = idx & 63;
      int m = m0 + r, kk = k0 + k;
      As[r * 66 + k] = (m < M && kk < kend) ? A[(size_t)m * lda + kk] : 0.f;
    }
    for (int idx = t; idx < 64 * 64; idx += 256) {
      int nr = idx >> 6, k = idx & 63;
      int nn = n0 + nr, kk = k0 + k;
      Bs[nr * 66 + k] = (nn < N && kk < kend) ? BT[(size_t)nn * ldb + kk] : 0.f;
    }
    __syncthreads();
#pragma unroll 8
    for (int k = 0; k < 64; k++) {
      float b = Bs[tx * 66 + k];
#pragma unroll
      for (int q = 0; q < 4; q++) acc[q] += As[(ty * 4 + q) * 66 + k] * b;
    }
    __syncthreads();
  }
  int col = n0 + tx;
  if (col >= N) return;
#pragma unroll
  for (int q = 0; q < 4; q++) {
    int row = m0 + ty * 4 + q;
    if (row < M) atomicAdd(&C[(size_t)row * ldc + col], acc[q]);
  }
}

__global__ void k_zero2(int* __restrict__ a, int* __restrict__ b, int n) {
  int tid = blockIdx.x * 256 + threadIdx.x;
  if (tid < n) { a[tid] = 0; b[tid] = 0; }
}

__global__ void k_zerof(float* __restrict__ a, int n) {
  int tid = blockIdx.x * 256 + threadIdx.x;
  if (tid < n) a[tid] = 0.f;
}

// ---------------------------------------------------------------------------
// GAT
// ---------------------------------------------------------------------------
__global__ void k_edge_e(const float* __restrict__ xl,
                         const float* __restrict__ xr,
                         const int* __restrict__ ei,
                         const float* __restrict__ att, float* __restrict__ e,
                         int E, int Etot) {
  __shared__ float attf[1024];
  int t = threadIdx.x;
  for (int i = t; i < 1024; i += 256) attf[i] = att[i];
  __syncthreads();
  int lane = t & 63;
  int eid = blockIdx.x * 4 + (t >> 6);
  if (eid >= Etot) return;
  int src = (eid < E) ? ei[eid] : (eid - E);
  int dst = (eid < E) ? ei[E + eid] : (eid - E);
  const float* pl = xl + (size_t)src * 1024;
  const float* pr = xr + (size_t)dst * 1024;
#pragma unroll
  for (int h = 0; h < 8; h++) {
    float a0 = pl[h * 128 + lane] + pr[h * 128 + lane];
    float a1 = pl[h * 128 + 64 + lane] + pr[h * 128 + 64 + lane];
    a0 = (a0 > 0.f) ? a0 : 0.2f * a0;
    a1 = (a1 > 0.f) ? a1 : 0.2f * a1;
    float p = a0 * attf[h * 128 + lane] + a1 * attf[h * 128 + 64 + lane];
#pragma unroll
    for (int off = 32; off; off >>= 1) p += __shfl_xor(p, off);
    if (lane == 0) e[(size_t)eid * 8 + h] = p;
  }
}

__global__ void k_count(const int* __restrict__ ei, int* __restrict__ cnt,
                        int E, int Etot) {
  int tid = blockIdx.x * 256 + threadIdx.x;
  if (tid >= Etot) return;
  int dst = (tid < E) ? ei[E + tid] : (tid - E);
  atomicAdd(&cnt[dst], 1);
}

__global__ void k_scan(const int* __restrict__ cnt, int* __restrict__ rowstart,
                       int Nn) {
  __shared__ int part[257];
  int t = threadIdx.x;
  int chunk = (Nn + 255) / 256;
  int b = t * chunk;
  int en = b + chunk; if (en > Nn) en = Nn;
  int s = 0;
  for (int i = b; i < en; i++) s += cnt[i];
  part[t] = s;
  __syncthreads();
  if (t == 0) {
    int acc = 0;
    for (int i = 0; i < 256; i++) { int v = part[i]; part[i] = acc; acc += v; }
    part[256] = acc;
  }
  __syncthreads();
  int run = part[t];
  for (int i = b; i < en; i++) { rowstart[i] = run; run += cnt[i]; }
  if (t == 0) rowstart[Nn] = part[256];
}

__global__ void k_scatter(const int* __restrict__ ei,
                          const int* __restrict__ rowstart,
                          int* __restrict__ cur, int* __restrict__ csr, int E,
                          int Etot) {
  int tid = blockIdx.x * 256 + threadIdx.x;
  if (tid >= Etot) return;
  int dst = (tid < E) ? ei[E + tid] : (tid - E);
  int p = atomicAdd(&cur[dst], 1);
  unsigned idx = (unsigned)(rowstart[dst] + p);
  if (idx < (unsigned)Etot) csr[idx] = tid;
}

__global__ void k_softmax(const float* __restrict__ e,
                          const int* __restrict__ csr,
                          const int* __restrict__ rowstart,
                          float* __restrict__ wgt, int Nn, int Etot) {
  int t = threadIdx.x;
  int lane = t & 63;
  int d = blockIdx.x * 4 + (t >> 6);
  if (d >= Nn) return;
  int rs = rowstart[d], re = rowstart[d + 1];
  for (int h = 0; h < 8; h++) {
    float mx = -3.0e38f;
    for (int i = rs + lane; i < re; i += 64) {
      unsigned eid = (unsigned)csr[i];
      if (eid < (unsigned)Etot) mx = fmaxf(mx, e[(size_t)eid * 8 + h]);
    }
#pragma unroll
    for (int off = 32; off; off >>= 1) mx = fmaxf(mx, __shfl_xor(mx, off));
    if (mx < -1.0e37f) mx = 0.f;
    float s = 0.f;
    for (int i = rs + lane; i < re; i += 64) {
      unsigned eid = (unsigned)csr[i];
      if (eid < (unsigned)Etot) s += expf(e[(size_t)eid * 8 + h] - mx);
    }
#pragma unroll
    for (int off = 32; off; off >>= 1) s += __shfl_xor(s, off);
    float inv = (s > 0.f) ? 1.f / s : 0.f;
    for (int i = rs + lane; i < re; i += 64) {
      unsigned eid = (unsigned)csr[i];
      if (eid < (unsigned)Etot)
        wgt[(size_t)eid * 8 + h] = expf(e[(size_t)eid * 8 + h] - mx) * inv;
    }
  }
}

__global__ void k_aggregate(const float* __restrict__ wgt,
                            const float* __restrict__ xl,
                            const int* __restrict__ ei,
                            const int* __restrict__ csr,
                            const int* __restrict__ rowstart,
                            const float* __restrict__ gbias,
                            float* __restrict__ res, int E, int Etot) {
  int d = blockIdx.x;
  int t = threadIdx.x;
  int c = t & 127, hb = t >> 7;
  int rs = rowstart[d], re = rowstart[d + 1];
  float acc[4] = {0.f, 0.f, 0.f, 0.f};
  for (int i = rs; i < re; i++) {
    unsigned eid = (unsigned)csr[i];
    if (eid >= (unsigned)Etot) continue;
    int src = (eid < (unsigned)E) ? ei[eid] : (int)(eid - E);
    const float* px = xl + (size_t)src * 1024 + hb * 512 + c;
    const float* pw = wgt + (size_t)eid * 8 + hb * 4;
#pragma unroll
    for (int q = 0; q < 4; q++) acc[q] += pw[q] * px[q * 128];
  }
#pragma unroll
  for (int q = 0; q < 4; q++) {
    int idx = (hb * 4 + q) * 128 + c;
    res[(size_t)d * 1024 + idx] = acc[q] + gbias[idx];
  }
}

// ---------------------------------------------------------------------------
// CNN: f32 in, f32 out to d_out (stride 2778), bf16 emb (stride 2784, padded)
// ---------------------------------------------------------------------------
__global__ void k_cnn(const float* __restrict__ res,
                      const float* __restrict__ cw1, const float* __restrict__ cb1,
                      const float* __restrict__ cw4, const float* __restrict__ cb4,
                      const float* __restrict__ cw16, const float* __restrict__ cb16,
                      const float* __restrict__ cw32, const float* __restrict__ cb32,
                      float* __restrict__ outc, u16* __restrict__ emb) {
  __shared__ float xs[1024];
  __shared__ float wc[2544];
  __shared__ float cb[24];
  int t = threadIdx.x, node = blockIdx.x;
  for (int i = t; i < 1024; i += 256) xs[i] = res[(size_t)node * 1024 + i];
  for (int i = t; i < 48; i += 256) wc[i] = cw1[i];
  for (int i = t; i < 192; i += 256) wc[48 + i] = cw4[i];
  for (int i = t; i < 768; i += 256) wc[240 + i] = cw16[i];
  for (int i = t; i < 1536; i += 256) wc[1008 + i] = cw32[i];
  if (t < 6) {
    cb[t] = cb1[t];
    cb[6 + t] = cb4[t];
    cb[12 + t] = cb16[t];
    cb[18 + t] = cb32[t];
  }
  __syncthreads();
  for (int o = t; o < 2778; o += 256) {
    int k, W, base, boff, rr;
    if (o < 768)       { k = 1;  W = 128; base = 0;    boff = 0;  rr = o; }
    else if (o < 1518) { k = 4;  W = 125; base = 48;   boff = 6;  rr = o - 768; }
    else if (o < 2196) { k = 16; W = 113; base = 240;  boff = 12; rr = o - 1518; }
    else               { k = 32; W = 97;  base = 1008; boff = 18; rr = o - 2196; }
    int oc = rr / W, wp = rr - oc * W;
    const float* wgt = &wc[base + oc * 8 * k];
    float v = cb[boff + oc];
    for (int h = 0; h < 8; h++)
      for (int j = 0; j < k; j++) v += xs[h * 128 + wp + j] * wgt[h * k + j];
    v = fmaxf(v, 0.f);
    outc[(size_t)node * 2778 + o] = v;
    emb[(size_t)node * 2784 + o] = f2b(v);
  }
  if (t < 6) emb[(size_t)node * 2784 + 2778 + t] = 0;  // zero K-pad
}

// ---------------------------------------------------------------------------
__global__ void k_gemv_sig(const u16* __restrict__ hh3,
                           const u16* __restrict__ w4, float* __restrict__ pred,
                           int M, int K, int ldk) {
  __shared__ float ws[464];
  int t = threadIdx.x;
  for (int i = t; i < K; i += 256) ws[i] = b2f(w4[i]);
  __syncthreads();
  int lane = t & 63;
  int m = blockIdx.x * 4 + (t >> 6);
  if (m >= M) return;
  const u16* p = hh3 + (size_t)m * ldk;
  float s = 0.f;
  for (int i = lane; i < K; i += 64) s += b2f(p[i]) * ws[i];
#pragma unroll
  for (int off = 32; off; off >>= 1) s += __shfl_xor(s, off);
  if (!(s == s)) s = 0.f;
  s = fminf(fmaxf(s, -30.f), 30.f);
  if (lane == 0) pred[m] = 1.f / (1.f + expf(-s));
}

__global__ void k_labels(float* __restrict__ lab, int P) {
  int tid = blockIdx.x * 256 + threadIdx.x;
  if (tid < 2 * P) lab[tid] = (tid < P) ? 1.f : 0.f;
}

__global__ void k_sentinel(float* __restrict__ pred, int M, float val) {
  int tid = blockIdx.x * 256 + threadIdx.x;
  if (tid < M) pred[tid] = val;
}

// ---------------------------------------------------------------------------
extern "C" void kernel_launch(void* const* d_in, const int* in_sizes, int n_in,
                              void* d_out, int out_size, void* d_ws,
                              size_t ws_size, hipStream_t stream) {
  (void)in_sizes; (void)n_in; (void)out_size;
  const int* ei = (const int*)d_in[2];
  const int* posp = (const int*)d_in[3];
  const int* negp = (const int*)d_in[4];

  const int E = 80000, ET = 82300, P = 40000, M = 80000;

  float* outp = (float*)d_out;
  float* outl = outp + 80000;
  float* outc = outp + 160000;

  k_labels<<<(2 * P + 255) / 256, 256, 0, stream>>>(outl, P);

  char* base = (char*)d_ws;
  size_t off = 0;
  auto alloc = [&](size_t bytes) -> void* {
    void* p = base + off;
    off = (off + bytes + 255) & ~(size_t)255;
    return p;
  };
  // front-end f32 copies
  float* mic_f = (float*)alloc((size_t)1500 * 1500 * 4);
  float* dis_f = (float*)alloc((size_t)800 * 800 * 4);
  float* WmT_f = (float*)alloc((size_t)128 * 1500 * 4);
  float* WdT_f = (float*)alloc((size_t)128 * 800 * 4);
  float* WlT_f = (float*)alloc((size_t)1024 * 128 * 4);
  float* WrT_f = (float*)alloc((size_t)1024 * 128 * 4);
  float* bl_f = (float*)alloc(1024 * 4);
  float* br_f = (float*)alloc(1024 * 4);
  float* att_f = (float*)alloc(1024 * 4);
  float* gbias_f = (float*)alloc(1024 * 4);
  float* cw1_f = (float*)alloc(48 * 4);
  float* cb1_f = (float*)alloc(6 * 4);
  float* cw4_f = (float*)alloc(192 * 4);
  float* cb4_f = (float*)alloc(6 * 4);
  float* cw16_f = (float*)alloc(768 * 4);
  float* cb16_f = (float*)alloc(6 * 4);
  float* cw32_f = (float*)alloc(1536 * 4);
  float* cb32_f = (float*)alloc(6 * 4);
  // MLP bf16 weights: rows padded to 256-mult, K padded to 64-mult (even
  // tile count: 2816/1408/768), zero-filled
  u16* m1T = (u16*)alloc((size_t)1536 * 2816 * 2);  // N 1389->1536, K->2816
  u16* m2T = (u16*)alloc((size_t)768 * 1408 * 2);   // N 694->768,  K->1408
  u16* m3T = (u16*)alloc((size_t)512 * 768 * 2);    // N 463->512,  K->768
  u16* mb1_b = (u16*)alloc(1389 * 2);
  u16* mb2_b = (u16*)alloc(694 * 2);
  u16* mb3_b = (u16*)alloc(463 * 2);
  u16* mw4_b = (u16*)alloc(463 * 2);
  // intermediates
  float* hbuf = (float*)alloc((size_t)2300 * 128 * 4);
  float* xlf = (float*)alloc((size_t)2300 * 1024 * 4);
  float* xrf = (float*)alloc((size_t)2300 * 1024 * 4);
  float* resf = xrf;  // xr dead after k_edge_e
  float* ebuf = (float*)alloc((size_t)ET * 8 * 4);
  float* wbuf = (float*)alloc((size_t)ET * 8 * 4);
  u16* emb = (u16*)alloc((size_t)2300 * 2784 * 2);
  int* cnt = (int*)alloc(2300 * 4);
  int* rowst = (int*)alloc(2304 * 4);
  int* cur = (int*)alloc(2300 * 4);
  int* csr = (int*)alloc((size_t)ET * 4);
  size_t fixed_end = off;

  // chunk: feats (R x 2816) + hh1 (R x 1408); hh2 ALIASES feats (feats is
  // dead after L1; per-chunk: feats->L1->hh1, hh1->L2->hh2(=feats),
  // hh2->L3->hh1, gemv(hh1)). R multiple of 256.
  const size_t per_row = (size_t)(2816 + 1408) * 2;
  size_t avail = (ws_size > fixed_end) ? (ws_size - fixed_end) : 0;
  long long Rll = (long long)(avail / per_row);
  int R = (Rll > M) ? M : (int)Rll;
  R &= ~255;
  if (R > 21760) R = 21760;  // keep feats chunk L3-fittable
  if (fixed_end > ws_size || R < 256) {
    k_sentinel<<<(M + 255) / 256, 256, 0, stream>>>(outp, M, 0.25f);
    return;
  }
  u16* feats = (u16*)(base + fixed_end);
  u16* hh1 = feats + (size_t)R * 2816;
  u16* hh2 = feats;  // alias: L2 output overwrites dead feats

  k_zero2<<<(2300 + 255) / 256, 256, 0, stream>>>(cnt, cur, 2300);
  k_zerof<<<(2300 * 128 + 255) / 256, 256, 0, stream>>>(hbuf, 2300 * 128);

  // ---- canonicalize inputs ----
  cvt_f<<<(2250000 + 255) / 256, 256, 0, stream>>>(d_in[0], mic_f, 2250000);
  cvt_f<<<(640000 + 255) / 256, 256, 0, stream>>>(d_in[1], dis_f, 640000);
  cvt_f_t<<<(192000 + 255) / 256, 256, 0, stream>>>(d_in[6], WmT_f, 1500, 128);
  cvt_f_t<<<(102400 + 255) / 256, 256, 0, stream>>>(d_in[7], WdT_f, 800, 128);
  cvt_f_t<<<(131072 + 255) / 256, 256, 0, stream>>>(d_in[8], WlT_f, 128, 1024);
  cvt_f<<<4, 256, 0, stream>>>(d_in[9], bl_f, 1024);
  cvt_f_t<<<(131072 + 255) / 256, 256, 0, stream>>>(d_in[10], WrT_f, 128, 1024);
  cvt_f<<<4, 256, 0, stream>>>(d_in[11], br_f, 1024);
  cvt_f<<<4, 256, 0, stream>>>(d_in[12], att_f, 1024);
  cvt_f<<<4, 256, 0, stream>>>(d_in[13], gbias_f, 1024);
  cvt_f<<<1, 256, 0, stream>>>(d_in[14], cw1_f, 48);
  cvt_f<<<1, 256, 0, stream>>>(d_in[15], cb1_f, 6);
  cvt_f<<<1, 256, 0, stream>>>(d_in[16], cw4_f, 192);
  cvt_f<<<1, 256, 0, stream>>>(d_in[17], cb4_f, 6);
  cvt_f<<<3, 256, 0, stream>>>(d_in[18], cw16_f, 768);
  cvt_f<<<1, 256, 0, stream>>>(d_in[19], cb16_f, 6);
  cvt_f<<<6, 256, 0, stream>>>(d_in[20], cw32_f, 1536);
  cvt_f<<<1, 256, 0, stream>>>(d_in[21], cb32_f, 6);
  cvt_b_tt<<<dim3(88, 48), 256, 0, stream>>>(d_in[22], m1T, 2778, 1389, 2816,
                                             1536);
  cvt_b<<<(1389 + 255) / 256, 256, 0, stream>>>(d_in[23], mb1_b, 1389);
  cvt_b_tt<<<dim3(44, 24), 256, 0, stream>>>(d_in[24], m2T, 1389, 694, 1408,
                                             768);
  cvt_b<<<(694 + 255) / 256, 256, 0, stream>>>(d_in[25], mb2_b, 694);
  cvt_b_tt<<<dim3(24, 16), 256, 0, stream>>>(d_in[26], m3T, 694, 463, 768, 512);
  cvt_b<<<(463 + 255) / 256, 256, 0, stream>>>(d_in[27], mb3_b, 463);
  cvt_b<<<(463 + 255) / 256, 256, 0, stream>>>(d_in[28], mw4_b, 463);

  // ---- front end ----
  // mic/dis: K-split (chunk 192) into pre-zeroed hbuf via atomicAdd
  vgemm_ks<<<dim3(2, 94, 8), 256, 0, stream>>>(mic_f, WmT_f, hbuf, 1500, 128,
                                               1500, 1500, 1500, 128, 192);
  vgemm_ks<<<dim3(2, 50, 5), 256, 0, stream>>>(dis_f, WdT_f,
                                               hbuf + (size_t)1500 * 128, 800,
                                               128, 800, 800, 800, 128, 192);
  vgemm_f<<<dim3(16, 144), 256, 0, stream>>>(hbuf, WlT_f, bl_f, xlf, 2300,
                                             1024, 128, 128, 128, 1024);
  vgemm_f<<<dim3(16, 144), 256, 0, stream>>>(hbuf, WrT_f, br_f, xrf, 2300,
                                             1024, 128, 128, 128, 1024);

  k_edge_e<<<(ET + 3) / 4, 256, 0, stream>>>(xlf, xrf, ei, att_f, ebuf, E, ET);
  k_count<<<(ET + 255) / 256, 256, 0, stream>>>(ei, cnt, E, ET);
  k_scan<<<1, 256, 0, stream>>>(cnt, rowst, 2300);
  k_scatter<<<(ET + 255) / 256, 256, 0, stream>>>(ei, rowst, cur, csr, E, ET);
  k_softmax<<<(2300 + 3) / 4, 256, 0, stream>>>(ebuf, csr, rowst, wbuf, 2300, ET);
  k_aggregate<<<2300, 256, 0, stream>>>(wbuf, xlf, ei, csr, rowst, gbias_f,
                                        resf, E, ET);

  k_cnn<<<2300, 256, 0, stream>>>(resf, cw1_f, cb1_f, cw4_f, cb4_f, cw16_f,
                                  cb16_f, cw32_f, cb32_f, outc, emb);

  // ---- MLP: feats precompute + 8-phase 256-tile MFMA GEMMs, chunked ----
  for (int c0 = 0; c0 < M; c0 += R) {
    int rows = (M - c0 < R) ? (M - c0) : R;
    int gby = (rows + 255) / 256;
    k_feats<<<((size_t)rows * 352 + 255) / 256, 256, 0, stream>>>(
        emb, posp, negp, P, c0, rows, feats);
    mgemm256<<<dim3(6, gby), 512, 0, stream>>>(feats, m1T, mb1_b, hh1, rows,
                                               1389, 2816, 2816, 2816, 1408,
                                               0.01f);
    mgemm256<<<dim3(3, gby), 512, 0, stream>>>(hh1, m2T, mb2_b, hh2, rows, 694,
                                               1408, 1408, 1408, 768, 0.01f);
    mgemm256<<<dim3(2, gby), 512, 0, stream>>>(hh2, m3T, mb3_b, hh1, rows, 463,
                                               768, 768, 768, 480, 0.01f);
    k_gemv_sig<<<(rows + 3) / 4, 256, 0, stream>>>(hh1, mw4_b, outp + c0, rows,
                                                   463, 480);
  }
}

// Round 12
// 1881.298 us; speedup vs baseline: 1.3351x; 1.0598x over previous
//
#include <hip/hip_runtime.h>

// ===========================================================================
// GAT_CNN_DASE :: gfx950 :: R22.
// R21 post-mortem: hh2-alias/chunk win was NULL (1993.7 vs 1993.0) -- R18
// already ran 4 chunks (workspace allowed R~21k); FETCH 375->396MB confirms
// R merely grew 20992->21760. Alias kept (harmless).
// State: L1 mgemm ~650us @46% MfmaUtil = structural floor for this
// decomposition (6 consecutive levers A/B'd null/negative). Remaining
// ~1340us = long tail of sub-174us dispatches + ~45 launches, 16 of them
// tiny (6..1536 elems) costing ~2-5us launch gap each on the serial stream.
// R22: launch batching, zero numerics change. cvt_batch_f (12 arrays, 1
// launch), cvt_batch_b (4 arrays, 1 launch), k_init (labels+cnt/cur+hbuf,
// 1 launch). Setup launches 28 -> 12. All heavy kernels byte-identical.
// ===========================================================================

typedef unsigned short u16;
typedef __attribute__((ext_vector_type(8))) short bf16x8;
typedef __attribute__((ext_vector_type(4))) float f32x4;

__device__ __forceinline__ float b2f(u16 u) {
  unsigned v = ((unsigned)u) << 16;
  return __builtin_bit_cast(float, v);
}
__device__ __forceinline__ u16 f2b(float f) {
  unsigned x = __builtin_bit_cast(unsigned, f);
  x += 0x7fffu + ((x >> 16) & 1u);
  return (u16)(x >> 16);
}

// async global->LDS, 16B per lane; LDS dest = wave-uniform base + lane*16
__device__ __forceinline__ void async_ld16(const u16* g, u16* l) {
  __builtin_amdgcn_global_load_lds(
      (const __attribute__((address_space(1))) void*)g,
      (__attribute__((address_space(3))) void*)l, 16, 0, 0);
}

// bf16 data: ~100% of u16s have exponent in [100,140]; f32-as-u16: ~58%.
__device__ __forceinline__ int sniff_bf16(const void* p, int n) {
  const u16* pu = (const u16*)p;
  int ns = n < 128 ? n : 128;
  int sane = 0, nz = 0;
  for (int i = 0; i < ns; i++) {
    u16 v = pu[i];
    if (v) nz++;
    int e = (v >> 7) & 0xFF;
    if (e >= 100 && e <= 140) sane++;
  }
  return (nz == 0) || (sane * 8 >= ns * 7);
}
__device__ __forceinline__ float ld_any(const void* p, size_t i, int isbf) {
  return isbf ? b2f(((const u16*)p)[i]) : ((const float*)p)[i];
}

__global__ void cvt_f(const void* __restrict__ in, float* __restrict__ out,
                      int n) {
  __shared__ int sbf;
  if (threadIdx.x == 0) sbf = sniff_bf16(in, n);
  __syncthreads();
  int tid = blockIdx.x * 256 + threadIdx.x;
  if (tid < n) out[tid] = ld_any(in, tid, sbf);
}
// in[k*N+n] -> out[n*K+k] (small front-end weights)
__global__ void cvt_f_t(const void* __restrict__ in, float* __restrict__ out,
                        int K, int N) {
  __shared__ int sbf;
  if (threadIdx.x == 0) sbf = sniff_bf16(in, K * N);
  __syncthreads();
  int tid = blockIdx.x * 256 + threadIdx.x;
  if (tid >= K * N) return;
  int nn = tid / K, k = tid - nn * K;
  out[tid] = ld_any(in, (size_t)k * N + nn, sbf);
}
// tiled transpose-convert: in K x N -> out Npad x Kpad bf16, zero-padded.
__global__ void cvt_b_tt(const void* __restrict__ in, u16* __restrict__ out,
                         int K, int N, int Kpad, int Npad) {
  __shared__ int sbf;
  __shared__ float tile[32][33];
  if (threadIdx.x == 0) sbf = sniff_bf16(in, K * N);
  __syncthreads();
  int k0 = blockIdx.x * 32, n0 = blockIdx.y * 32;
  int tx = threadIdx.x & 31, ty = threadIdx.x >> 5;  // 32x8
#pragma unroll
  for (int i = 0; i < 32; i += 8) {
    int k = k0 + ty + i, n = n0 + tx;
    tile[ty + i][tx] =
        (k < K && n < N) ? ld_any(in, (size_t)k * N + n, sbf) : 0.f;
  }
  __syncthreads();
#pragma unroll
  for (int i = 0; i < 32; i += 8) {
    int n = n0 + ty + i, k = k0 + tx;
    if (n < Npad && k < Kpad) out[(size_t)n * Kpad + k] = f2b(tile[tx][ty + i]);
  }
}

// ---------------------------------------------------------------------------
// batched small conversions: one block per array (R22 launch batching)
// ---------------------------------------------------------------------------
__global__ void cvt_batch_f(
    const void* s0, float* o0, const void* s1, float* o1, const void* s2,
    float* o2, const void* s3, float* o3, const void* s4, float* o4,
    const void* s5, float* o5, const void* s6, float* o6, const void* s7,
    float* o7, const void* s8, float* o8, const void* s9, float* o9,
    const void* s10, float* o10, const void* s11, float* o11) {
  const void* src;
  float* dst;
  int n;
  switch (blockIdx.x) {
    case 0:  src = s0;  dst = o0;  n = 1024; break;  // bl
    case 1:  src = s1;  dst = o1;  n = 1024; break;  // br
    case 2:  src = s2;  dst = o2;  n = 1024; break;  // att
    case 3:  src = s3;  dst = o3;  n = 1024; break;  // gbias
    case 4:  src = s4;  dst = o4;  n = 48;   break;  // cw1
    case 5:  src = s5;  dst = o5;  n = 6;    break;  // cb1
    case 6:  src = s6;  dst = o6;  n = 192;  break;  // cw4
    case 7:  src = s7;  dst = o7;  n = 6;    break;  // cb4
    case 8:  src = s8;  dst = o8;  n = 768;  break;  // cw16
    case 9:  src = s9;  dst = o9;  n = 6;    break;  // cb16
    case 10: src = s10; dst = o10; n = 1536; break;  // cw32
    default: src = s11; dst = o11; n = 6;    break;  // cb32
  }
  __shared__ int sbf;
  if (threadIdx.x == 0) sbf = sniff_bf16(src, n);
  __syncthreads();
  for (int i = threadIdx.x; i < n; i += 256) dst[i] = ld_any(src, i, sbf);
}

__global__ void cvt_batch_b(const void* s0, u16* o0, const void* s1, u16* o1,
                            const void* s2, u16* o2, const void* s3, u16* o3) {
  const void* src;
  u16* dst;
  int n;
  switch (blockIdx.x) {
    case 0:  src = s0; dst = o0; n = 1389; break;  // mb1
    case 1:  src = s1; dst = o1; n = 694;  break;  // mb2
    case 2:  src = s2; dst = o2; n = 463;  break;  // mb3
    default: src = s3; dst = o3; n = 463;  break;  // mw4
  }
  __shared__ int sbf;
  if (threadIdx.x == 0) sbf = sniff_bf16(src, n);
  __syncthreads();
  for (int i = threadIdx.x; i < n; i += 256) dst[i] = f2b(ld_any(src, i, sbf));
}

// fused init: labels + cnt/cur zero + hbuf zero (R22)
__global__ void k_init(float* __restrict__ lab, int P2, int Ph,
                       int* __restrict__ cnt, int* __restrict__ cur, int ncnt,
                       float* __restrict__ hb, int nh) {
  int tid = blockIdx.x * 256 + threadIdx.x;
  if (tid < P2) lab[tid] = (tid < Ph) ? 1.f : 0.f;
  if (tid < ncnt) { cnt[tid] = 0; cur[tid] = 0; }
  if (tid < nh) hb[tid] = 0.f;
}

// ---------------------------------------------------------------------------
// feats chunk: feats[r][0..2784) = emb[p0[..]] * emb[1500+p1[..]], cols
// 2784..2816 zeroed (K padded to 2816 for BK=64). One thread per 8 elems.
// ---------------------------------------------------------------------------
__global__ void k_feats(const u16* __restrict__ emb,
                        const int* __restrict__ posp,
                        const int* __restrict__ negp, int npos, int mbase,
                        int rows, u16* __restrict__ feats) {
  int idx = blockIdx.x * 256 + threadIdx.x;
  int r = idx / 352, c8 = (idx - r * 352) * 8;
  if (r >= rows) return;
  if (c8 >= 2784) {
    bf16x8 z = {0, 0, 0, 0, 0, 0, 0, 0};
    *(bf16x8*)(feats + (size_t)r * 2816 + c8) = z;
    return;
  }
  int g = mbase + r;
  const int* pp = (g < npos) ? (posp + 2 * g) : (negp + 2 * (g - npos));
  bf16x8 x = *(const bf16x8*)(emb + (size_t)pp[0] * 2784 + c8);
  bf16x8 y = *(const bf16x8*)(emb + (size_t)(1500 + pp[1]) * 2784 + c8);
  bf16x8 v;
#pragma unroll
  for (int j = 0; j < 8; j++)
    ((u16*)&v)[j] = f2b(b2f((u16)x[j]) * b2f((u16)y[j]));
  *(bf16x8*)(feats + (size_t)r * 2816 + c8) = v;
}

// ---------------------------------------------------------------------------
// mgemm256 (8-phase, 1 barrier/phase, reg double-buffer, no setprio) -- the
// R18 best-known kernel, byte-identical. 256x256 tile, 512 thr (8 waves,
// 2Mx4N), wave tile 128x64, BK=64 as two K-32 slabs. LDS slabs [256][32]
// u16, swizzled chunk c' = c ^ ((row>>1)&3). Per phase: barrier -> stage ->
// [vmcnt(6) even] -> ds_reads for NEXT phase into alternate reg set ->
// sched_barrier(0) -> 16 MFMA on current set. C = lrelu(A@B + bias);
// zero-fills cols [N, ldc). Requires: Kpad % 128 == 0 (>=256), A rows alloc
// >= gby*256, BT rows alloc >= gridDim.x*256 zero-padded.
// ---------------------------------------------------------------------------
__global__ __launch_bounds__(512, 2) void mgemm256(
    const u16* __restrict__ A, const u16* __restrict__ BT,
    const u16* __restrict__ bias, u16* __restrict__ C, int M, int N, int Kpad,
    int lda, int ldb, int ldc, float slope) {
  // 8 slabs of 16KB: A(p,kk) at (p*2+kk)*8192 u16; B same at +32768.
  __shared__ u16 lds[65536];
  u16* As = lds;
  u16* Bs = lds + 32768;
  const int t = threadIdx.x;
  const int lane = t & 63, wave = t >> 6;
  const int quad = lane >> 4, l16 = lane & 15;
  const int wm = wave >> 2, wn = wave & 3;
  const int m0 = blockIdx.y * 256, n0 = blockIdx.x * 256;

  // staging: thread t -> row r0 = t>>2 (and +128 on 2nd call), LDS 16B-chunk
  // c' = t&3; source chunk c = c' ^ ((r0>>1)&3) = (t&3) ^ ((t>>3)&3).
  const int r0 = t >> 2;
  const int csrc = (t & 3) ^ ((t >> 3) & 3);
  const u16* Ap = A + (size_t)(m0 + r0) * lda + csrc * 8;
  const u16* Bp = BT + (size_t)(n0 + r0) * ldb + csrc * 8;
  const size_t a128 = (size_t)128 * lda, b128 = (size_t)128 * ldb;
  const int dst = wave * 512;  // u16 offset of wave's 1KB within a call

  // reads: row = (wm*128|wn*64) + i*16 + l16; swizzled chunk = quad^((l16>>1)&3)
  const int rsw = (quad ^ ((l16 >> 1) & 3)) * 8;
  const int a_base = (wm * 128 + l16) * 32 + rsw;  // + i*512
  const int b_base = (wn * 64 + l16) * 32 + rsw;   // + j*512

  f32x4 zero4 = {0.f, 0.f, 0.f, 0.f};
  f32x4 acc[8][4];
#pragma unroll
  for (int i = 0; i < 8; i++)
#pragma unroll
    for (int j = 0; j < 4; j++) acc[i][j] = zero4;

  const int iters = Kpad >> 7;  // 2 K-64 tiles per iteration

  bf16x8 ra0[4], ra1[4], rb0[4], rb1[4];

#define ST_A(slab, kofs)                              \
  {                                                   \
    u16* d_ = As + (slab) * 8192 + dst;               \
    async_ld16(Ap + (kofs), d_);                      \
    async_ld16(Ap + a128 + (kofs), d_ + 4096);        \
  }
#define ST_B(slab, kofs)                              \
  {                                                   \
    u16* d_ = Bs + (slab) * 8192 + dst;               \
    async_ld16(Bp + (kofs), d_);                      \
    async_ld16(Bp + b128 + (kofs), d_ + 4096);        \
  }
#define LDA4(rr, slab, i0)                                                   \
  _Pragma("unroll") for (int i = 0; i < 4; i++) rr[i] =                      \
      *(const bf16x8*)(As + (slab) * 8192 + a_base + ((i0) + i) * 512);
#define LDB4(rr, slab)                                                       \
  _Pragma("unroll") for (int j = 0; j < 4; j++) rr[j] =                      \
      *(const bf16x8*)(Bs + (slab) * 8192 + b_base + j * 512);
#define BAR __builtin_amdgcn_s_barrier();
#define SBAR __builtin_amdgcn_sched_barrier(0);
#define MFMA16(AS, BS, A0)                                                   \
  _Pragma("unroll") for (int i = 0; i < 4; i++)                              \
      _Pragma("unroll") for (int j = 0; j < 4; j++) acc[(A0) + i][j] =       \
          __builtin_amdgcn_mfma_f32_16x16x32_bf16(AS[i], BS[j],              \
                                                  acc[(A0) + i][j], 0, 0, 0);
#define WAIT6 asm volatile("s_waitcnt vmcnt(6)" ::: "memory");

  // ---- prologue: 6 halves: t0.Ak0,t0.Bk0,t0.Ak1,t0.Bk1,t1.Ak0,t1.Bk0 ----
  ST_A(0, 0);  ST_B(0, 0);
  ST_A(1, 32); ST_B(1, 32);
  ST_A(2, 64); ST_B(2, 64);
  asm volatile("s_waitcnt vmcnt(6)" ::: "memory");  // t0.Ak0/Bk0/Ak1 landed
  BAR;
  LDA4(ra0, 0, 0); LDB4(rb0, 0);  // reads for ph1

  for (int it = 0; it < iters - 1; ++it) {
    const size_t tb = (size_t)it * 128;  // K-elem base of T0=2*it
    // ph1: MFMA T0kk0 lo; reads ph2 (slab0 hi); stage T1.Ak1
    BAR; ST_A(3, tb + 96);          LDA4(ra1, 0, 4);               SBAR; MFMA16(ra0, rb0, 0);
    // ph2: MFMA T0kk0 hi; reads ph3 (slab1); stage T1.Bk1
    BAR; ST_B(3, tb + 96);  WAIT6;  LDA4(ra0, 1, 0); LDB4(rb1, 1); SBAR; MFMA16(ra1, rb0, 4);
    // ph3
    BAR; ST_A(0, tb + 128);         LDA4(ra1, 1, 4);               SBAR; MFMA16(ra0, rb1, 0);
    // ph4
    BAR; ST_B(0, tb + 128); WAIT6;  LDA4(ra0, 2, 0); LDB4(rb0, 2); SBAR; MFMA16(ra1, rb1, 4);
    // ph5
    BAR; ST_A(1, tb + 160);         LDA4(ra1, 2, 4);               SBAR; MFMA16(ra0, rb0, 0);
    // ph6
    BAR; ST_B(1, tb + 160); WAIT6;  LDA4(ra0, 3, 0); LDB4(rb1, 3); SBAR; MFMA16(ra1, rb0, 4);
    // ph7
    BAR; ST_A(2, tb + 192);         LDA4(ra1, 3, 4);               SBAR; MFMA16(ra0, rb1, 0);
    // ph8: reads next-iter ph1 (slab0 = T2.kk0, landed per ledger)
    BAR; ST_B(2, tb + 192); WAIT6;  LDA4(ra0, 0, 0); LDB4(rb0, 0); SBAR; MFMA16(ra1, rb1, 4);
  }

  // ---- peeled last iteration: stages only ph1/ph2, drain 8 -> 4 -> 0 ----
  {
    const size_t tb = (size_t)(iters - 1) * 128;
    BAR; ST_A(3, tb + 96);          LDA4(ra1, 0, 4);               SBAR; MFMA16(ra0, rb0, 0);
    BAR; ST_B(3, tb + 96);
    asm volatile("s_waitcnt vmcnt(8)" ::: "memory");
    LDA4(ra0, 1, 0); LDB4(rb1, 1);                                 SBAR; MFMA16(ra1, rb0, 4);
    BAR;                            LDA4(ra1, 1, 4);               SBAR; MFMA16(ra0, rb1, 0);
    BAR;
    asm volatile("s_waitcnt vmcnt(4)" ::: "memory");
    LDA4(ra0, 2, 0); LDB4(rb0, 2);                                 SBAR; MFMA16(ra1, rb1, 4);
    BAR;                            LDA4(ra1, 2, 4);               SBAR; MFMA16(ra0, rb0, 0);
    BAR;
    asm volatile("s_waitcnt vmcnt(0)" ::: "memory");
    LDA4(ra0, 3, 0); LDB4(rb1, 3);                                 SBAR; MFMA16(ra1, rb0, 4);
    BAR;                            LDA4(ra1, 3, 4);               SBAR; MFMA16(ra0, rb1, 0);
    BAR;                                                           SBAR; MFMA16(ra1, rb1, 4);
  }
#undef ST_A
#undef ST_B
#undef LDA4
#undef LDB4
#undef BAR
#undef SBAR
#undef MFMA16
#undef WAIT6

  // ---- epilogue ----
#pragma unroll
  for (int j = 0; j < 4; j++) {
    int col = n0 + wn * 64 + j * 16 + l16;
    if (col >= ldc) continue;
    float bv = 0.f;
    if (bias != nullptr && col < N) bv = b2f(bias[col]);
#pragma unroll
    for (int i = 0; i < 8; i++) {
#pragma unroll
      for (int r = 0; r < 4; r++) {
        int row = m0 + wm * 128 + i * 16 + quad * 4 + r;
        if (row >= M) continue;
        float v;
        if (col < N) {
          v = acc[i][j][r] + bv;
          v = (v > 0.f) ? v : v * slope;
        } else {
          v = 0.f;
        }
        C[(size_t)row * ldc + col] = f2b(v);
      }
    }
  }
}

// ---------------------------------------------------------------------------
// f32 VALU GEMM (front end, bias path; used where grid is already large)
// ---------------------------------------------------------------------------
__global__ __launch_bounds__(256) void vgemm_f(
    const float* __restrict__ A, const float* __restrict__ BT,
    const float* __restrict__ bias, float* __restrict__ C, int M, int N, int K,
    int lda, int ldb, int ldc) {
  __shared__ float As[16 * 66];
  __shared__ float Bs[64 * 66];
  const int t = threadIdx.x;
  const int m0 = blockIdx.y * 16, n0 = blockIdx.x * 64;
  const int tx = t & 63, ty = t >> 6;
  float acc[4] = {0.f, 0.f, 0.f, 0.f};
  for (int k0 = 0; k0 < K; k0 += 64) {
    for (int idx = t; idx < 16 * 64; idx += 256) {
      int r = idx >> 6, k = idx & 63;
      int m = m0 + r, kk = k0 + k;
      As[r * 66 + k] = (m < M && kk < K) ? A[(size_t)m * lda + kk] : 0.f;
    }
    for (int idx = t; idx < 64 * 64; idx += 256) {
      int nr = idx >> 6, k = idx & 63;
      int nn = n0 + nr, kk = k0 + k;
      Bs[nr * 66 + k] = (nn < N && kk < K) ? BT[(size_t)nn * ldb + kk] : 0.f;
    }
    __syncthreads();
#pragma unroll 8
    for (int k = 0; k < 64; k++) {
      float b = Bs[tx * 66 + k];
#pragma unroll
      for (int q = 0; q < 4; q++) acc[q] += As[(ty * 4 + q) * 66 + k] * b;
    }
    __syncthreads();
  }
  int col = n0 + tx;
  if (col >= N) return;
  float bv = (bias != nullptr) ? bias[col] : 0.f;
#pragma unroll
  for (int q = 0; q < 4; q++) {
    int row = m0 + ty * 4 + q;
    if (row < M) C[(size_t)row * ldc + col] = acc[q] + bv;
  }
}

// ---------------------------------------------------------------------------
// K-split f32 GEMM: z-grid over K-chunks, partials atomicAdd'd into
// pre-zeroed C (no bias). Fixes latency-bound small-grid GEMMs (R16).
// ---------------------------------------------------------------------------
__global__ __launch_bounds__(256) void vgemm_ks(
    const float* __restrict__ A, const float* __restrict__ BT,
    float* __restrict__ C, int M, int N, int K, int lda, int ldb, int ldc,
    int kchunk) {
  __shared__ float As[16 * 66];
  __shared__ float Bs[64 * 66];
  const int t = threadIdx.x;
  const int m0 = blockIdx.y * 16, n0 = blockIdx.x * 64;
  const int kbeg = blockIdx.z * kchunk;
  int kend = kbeg + kchunk;
  if (kend > K) kend = K;
  const int tx = t & 63, ty = t >> 6;
  float acc[4] = {0.f, 0.f, 0.f, 0.f};
  for (int k0 = kbeg; k0 < kend; k0 += 64) {
    for (int idx = t; idx < 16 * 64; idx += 256) {
      int r = idx >> 6, k = idx & 63;
      int m = m0 + r, kk = k0 + k;
      As[r * 66 + k] = (m < M && kk < kend) ? A[(size_t)m * lda + kk] : 0.f;
    }
    for (int idx = t; idx < 64 * 64; idx += 256) {
      int nr = idx >> 6, k = idx & 63;
      int nn = n0 + nr, kk = k0 + k;
      Bs[nr * 66 + k] = (nn < N && kk < kend) ? BT[(size_t)nn * ldb + kk] : 0.f;
    }
    __syncthreads();
#pragma unroll 8
    for (int k = 0; k < 64; k++) {
      float b = Bs[tx * 66 + k];
#pragma unroll
      for (int q = 0; q < 4; q++) acc[q] += As[(ty * 4 + q) * 66 + k] * b;
    }
    __syncthreads();
  }
  int col = n0 + tx;
  if (col >= N) return;
#pragma unroll
  for (int q = 0; q < 4; q++) {
    int row = m0 + ty * 4 + q;
    if (row < M) atomicAdd(&C[(size_t)row * ldc + col], acc[q]);
  }
}

// ---------------------------------------------------------------------------
// GAT
// ---------------------------------------------------------------------------
__global__ void k_edge_e(const float* __restrict__ xl,
                         const float* __restrict__ xr,
                         const int* __restrict__ ei,
                         const float* __restrict__ att, float* __restrict__ e,
                         int E, int Etot) {
  __shared__ float attf[1024];
  int t = threadIdx.x;
  for (int i = t; i < 1024; i += 256) attf[i] = att[i];
  __syncthreads();
  int lane = t & 63;
  int eid = blockIdx.x * 4 + (t >> 6);
  if (eid >= Etot) return;
  int src = (eid < E) ? ei[eid] : (eid - E);
  int dst = (eid < E) ? ei[E + eid] : (eid - E);
  const float* pl = xl + (size_t)src * 1024;
  const float* pr = xr + (size_t)dst * 1024;
#pragma unroll
  for (int h = 0; h < 8; h++) {
    float a0 = pl[h * 128 + lane] + pr[h * 128 + lane];
    float a1 = pl[h * 128 + 64 + lane] + pr[h * 128 + 64 + lane];
    a0 = (a0 > 0.f) ? a0 : 0.2f * a0;
    a1 = (a1 > 0.f) ? a1 : 0.2f * a1;
    float p = a0 * attf[h * 128 + lane] + a1 * attf[h * 128 + 64 + lane];
#pragma unroll
    for (int off = 32; off; off >>= 1) p += __shfl_xor(p, off);
    if (lane == 0) e[(size_t)eid * 8 + h] = p;
  }
}

__global__ void k_count(const int* __restrict__ ei, int* __restrict__ cnt,
                        int E, int Etot) {
  int tid = blockIdx.x * 256 + threadIdx.x;
  if (tid >= Etot) return;
  int dst = (tid < E) ? ei[E + tid] : (tid - E);
  atomicAdd(&cnt[dst], 1);
}

__global__ void k_scan(const int* __restrict__ cnt, int* __restrict__ rowstart,
                       int Nn) {
  __shared__ int part[257];
  int t = threadIdx.x;
  int chunk = (Nn + 255) / 256;
  int b = t * chunk;
  int en = b + chunk; if (en > Nn) en = Nn;
  int s = 0;
  for (int i = b; i < en; i++) s += cnt[i];
  part[t] = s;
  __syncthreads();
  if (t == 0) {
    int acc = 0;
    for (int i = 0; i < 256; i++) { int v = part[i]; part[i] = acc; acc += v; }
    part[256] = acc;
  }
  __syncthreads();
  int run = part[t];
  for (int i = b; i < en; i++) { rowstart[i] = run; run += cnt[i]; }
  if (t == 0) rowstart[Nn] = part[256];
}

__global__ void k_scatter(const int* __restrict__ ei,
                          const int* __restrict__ rowstart,
                          int* __restrict__ cur, int* __restrict__ csr, int E,
                          int Etot) {
  int tid = blockIdx.x * 256 + threadIdx.x;
  if (tid >= Etot) return;
  int dst = (tid < E) ? ei[E + tid] : (tid - E);
  int p = atomicAdd(&cur[dst], 1);
  unsigned idx = (unsigned)(rowstart[dst] + p);
  if (idx < (unsigned)Etot) csr[idx] = tid;
}

__global__ void k_softmax(const float* __restrict__ e,
                          const int* __restrict__ csr,
                          const int* __restrict__ rowstart,
                          float* __restrict__ wgt, int Nn, int Etot) {
  int t = threadIdx.x;
  int lane = t & 63;
  int d = blockIdx.x * 4 + (t >> 6);
  if (d >= Nn) return;
  int rs = rowstart[d], re = rowstart[d + 1];
  for (int h = 0; h < 8; h++) {
    float mx = -3.0e38f;
    for (int i = rs + lane; i < re; i += 64) {
      unsigned eid = (unsigned)csr[i];
      if (eid < (unsigned)Etot) mx = fmaxf(mx, e[(size_t)eid * 8 + h]);
    }
#pragma unroll
    for (int off = 32; off; off >>= 1) mx = fmaxf(mx, __shfl_xor(mx, off));
    if (mx < -1.0e37f) mx = 0.f;
    float s = 0.f;
    for (int i = rs + lane; i < re; i += 64) {
      unsigned eid = (unsigned)csr[i];
      if (eid < (unsigned)Etot) s += expf(e[(size_t)eid * 8 + h] - mx);
    }
#pragma unroll
    for (int off = 32; off; off >>= 1) s += __shfl_xor(s, off);
    float inv = (s > 0.f) ? 1.f / s : 0.f;
    for (int i = rs + lane; i < re; i += 64) {
      unsigned eid = (unsigned)csr[i];
      if (eid < (unsigned)Etot)
        wgt[(size_t)eid * 8 + h] = expf(e[(size_t)eid * 8 + h] - mx) * inv;
    }
  }
}

__global__ void k_aggregate(const float* __restrict__ wgt,
                            const float* __restrict__ xl,
                            const int* __restrict__ ei,
                            const int* __restrict__ csr,
                            const int* __restrict__ rowstart,
                            const float* __restrict__ gbias,
                            float* __restrict__ res, int E, int Etot) {
  int d = blockIdx.x;
  int t = threadIdx.x;
  int c = t & 127, hb = t >> 7;
  int rs = rowstart[d], re = rowstart[d + 1];
  float acc[4] = {0.f, 0.f, 0.f, 0.f};
  for (int i = rs; i < re; i++) {
    unsigned eid = (unsigned)csr[i];
    if (eid >= (unsigned)Etot) continue;
    int src = (eid < (unsigned)E) ? ei[eid] : (int)(eid - E);
    const float* px = xl + (size_t)src * 1024 + hb * 512 + c;
    const float* pw = wgt + (size_t)eid * 8 + hb * 4;
#pragma unroll
    for (int q = 0; q < 4; q++) acc[q] += pw[q] * px[q * 128];
  }
#pragma unroll
  for (int q = 0; q < 4; q++) {
    int idx = (hb * 4 + q) * 128 + c;
    res[(size_t)d * 1024 + idx] = acc[q] + gbias[idx];
  }
}

// ---------------------------------------------------------------------------
// CNN: f32 in, f32 out to d_out (stride 2778), bf16 emb (stride 2784, padded)
// ---------------------------------------------------------------------------
__global__ void k_cnn(const float* __restrict__ res,
                      const float* __restrict__ cw1, const float* __restrict__ cb1,
                      const float* __restrict__ cw4, const float* __restrict__ cb4,
                      const float* __restrict__ cw16, const float* __restrict__ cb16,
                      const float* __restrict__ cw32, const float* __restrict__ cb32,
                      float* __restrict__ outc, u16* __restrict__ emb) {
  __shared__ float xs[1024];
  __shared__ float wc[2544];
  __shared__ float cb[24];
  int t = threadIdx.x, node = blockIdx.x;
  for (int i = t; i < 1024; i += 256) xs[i] = res[(size_t)node * 1024 + i];
  for (int i = t; i < 48; i += 256) wc[i] = cw1[i];
  for (int i = t; i < 192; i += 256) wc[48 + i] = cw4[i];
  for (int i = t; i < 768; i += 256) wc[240 + i] = cw16[i];
  for (int i = t; i < 1536; i += 256) wc[1008 + i] = cw32[i];
  if (t < 6) {
    cb[t] = cb1[t];
    cb[6 + t] = cb4[t];
    cb[12 + t] = cb16[t];
    cb[18 + t] = cb32[t];
  }
  __syncthreads();
  for (int o = t; o < 2778; o += 256) {
    int k, W, base, boff, rr;
    if (o < 768)       { k = 1;  W = 128; base = 0;    boff = 0;  rr = o; }
    else if (o < 1518) { k = 4;  W = 125; base = 48;   boff = 6;  rr = o - 768; }
    else if (o < 2196) { k = 16; W = 113; base = 240;  boff = 12; rr = o - 1518; }
    else               { k = 32; W = 97;  base = 1008; boff = 18; rr = o - 2196; }
    int oc = rr / W, wp = rr - oc * W;
    const float* wgt = &wc[base + oc * 8 * k];
    float v = cb[boff + oc];
    for (int h = 0; h < 8; h++)
      for (int j = 0; j < k; j++) v += xs[h * 128 + wp + j] * wgt[h * k + j];
    v = fmaxf(v, 0.f);
    outc[(size_t)node * 2778 + o] = v;
    emb[(size_t)node * 2784 + o] = f2b(v);
  }
  if (t < 6) emb[(size_t)node * 2784 + 2778 + t] = 0;  // zero K-pad
}

// ---------------------------------------------------------------------------
__global__ void k_gemv_sig(const u16* __restrict__ hh3,
                           const u16* __restrict__ w4, float* __restrict__ pred,
                           int M, int K, int ldk) {
  __shared__ float ws[464];
  int t = threadIdx.x;
  for (int i = t; i < K; i += 256) ws[i] = b2f(w4[i]);
  __syncthreads();
  int lane = t & 63;
  int m = blockIdx.x * 4 + (t >> 6);
  if (m >= M) return;
  const u16* p = hh3 + (size_t)m * ldk;
  float s = 0.f;
  for (int i = lane; i < K; i += 64) s += b2f(p[i]) * ws[i];
#pragma unroll
  for (int off = 32; off; off >>= 1) s += __shfl_xor(s, off);
  if (!(s == s)) s = 0.f;
  s = fminf(fmaxf(s, -30.f), 30.f);
  if (lane == 0) pred[m] = 1.f / (1.f + expf(-s));
}

__global__ void k_sentinel(float* __restrict__ pred, int M, float val) {
  int tid = blockIdx.x * 256 + threadIdx.x;
  if (tid < M) pred[tid] = val;
}

// ---------------------------------------------------------------------------
extern "C" void kernel_launch(void* const* d_in, const int* in_sizes, int n_in,
                              void* d_out, int out_size, void* d_ws,
                              size_t ws_size, hipStream_t stream) {
  (void)in_sizes; (void)n_in; (void)out_size;
  const int* ei = (const int*)d_in[2];
  const int* posp = (const int*)d_in[3];
  const int* negp = (const int*)d_in[4];

  const int E = 80000, ET = 82300, P = 40000, M = 80000;

  float* outp = (float*)d_out;
  float* outl = outp + 80000;
  float* outc = outp + 160000;

  char* base = (char*)d_ws;
  size_t off = 0;
  auto alloc = [&](size_t bytes) -> void* {
    void* p = base + off;
    off = (off + bytes + 255) & ~(size_t)255;
    return p;
  };
  // front-end f32 copies
  float* mic_f = (float*)alloc((size_t)1500 * 1500 * 4);
  float* dis_f = (float*)alloc((size_t)800 * 800 * 4);
  float* WmT_f = (float*)alloc((size_t)128 * 1500 * 4);
  float* WdT_f = (float*)alloc((size_t)128 * 800 * 4);
  float* WlT_f = (float*)alloc((size_t)1024 * 128 * 4);
  float* WrT_f = (float*)alloc((size_t)1024 * 128 * 4);
  float* bl_f = (float*)alloc(1024 * 4);
  float* br_f = (float*)alloc(1024 * 4);
  float* att_f = (float*)alloc(1024 * 4);
  float* gbias_f = (float*)alloc(1024 * 4);
  float* cw1_f = (float*)alloc(48 * 4);
  float* cb1_f = (float*)alloc(6 * 4);
  float* cw4_f = (float*)alloc(192 * 4);
  float* cb4_f = (float*)alloc(6 * 4);
  float* cw16_f = (float*)alloc(768 * 4);
  float* cb16_f = (float*)alloc(6 * 4);
  float* cw32_f = (float*)alloc(1536 * 4);
  float* cb32_f = (float*)alloc(6 * 4);
  // MLP bf16 weights: rows padded to 256-mult, K padded to 64-mult (even
  // tile count: 2816/1408/768), zero-filled
  u16* m1T = (u16*)alloc((size_t)1536 * 2816 * 2);  // N 1389->1536, K->2816
  u16* m2T = (u16*)alloc((size_t)768 * 1408 * 2);   // N 694->768,  K->1408
  u16* m3T = (u16*)alloc((size_t)512 * 768 * 2);    // N 463->512,  K->768
  u16* mb1_b = (u16*)alloc(1389 * 2);
  u16* mb2_b = (u16*)alloc(694 * 2);
  u16* mb3_b = (u16*)alloc(463 * 2);
  u16* mw4_b = (u16*)alloc(463 * 2);
  // intermediates
  float* hbuf = (float*)alloc((size_t)2300 * 128 * 4);
  float* xlf = (float*)alloc((size_t)2300 * 1024 * 4);
  float* xrf = (float*)alloc((size_t)2300 * 1024 * 4);
  float* resf = xrf;  // xr dead after k_edge_e
  float* ebuf = (float*)alloc((size_t)ET * 8 * 4);
  float* wbuf = (float*)alloc((size_t)ET * 8 * 4);
  u16* emb = (u16*)alloc((size_t)2300 * 2784 * 2);
  int* cnt = (int*)alloc(2300 * 4);
  int* rowst = (int*)alloc(2304 * 4);
  int* cur = (int*)alloc(2300 * 4);
  int* csr = (int*)alloc((size_t)ET * 4);
  size_t fixed_end = off;

  // chunk: feats (R x 2816) + hh1 (R x 1408); hh2 ALIASES feats (feats is
  // dead after L1; per-chunk: feats->L1->hh1, hh1->L2->hh2(=feats),
  // hh2->L3->hh1, gemv(hh1)). R multiple of 256.
  const size_t per_row = (size_t)(2816 + 1408) * 2;
  size_t avail = (ws_size > fixed_end) ? (ws_size - fixed_end) : 0;
  long long Rll = (long long)(avail / per_row);
  int R = (Rll > M) ? M : (int)Rll;
  R &= ~255;
  if (R > 21760) R = 21760;  // keep feats chunk L3-fittable
  if (fixed_end > ws_size || R < 256) {
    k_sentinel<<<(M + 255) / 256, 256, 0, stream>>>(outp, M, 0.25f);
    return;
  }
  u16* feats = (u16*)(base + fixed_end);
  u16* hh1 = feats + (size_t)R * 2816;
  u16* hh2 = feats;  // alias: L2 output overwrites dead feats

  // fused init: labels + cnt/cur + hbuf (one launch)
  k_init<<<(2300 * 128 + 255) / 256, 256, 0, stream>>>(
      outl, 2 * P, P, cnt, cur, 2300, hbuf, 2300 * 128);

  // ---- canonicalize inputs ----
  cvt_f<<<(2250000 + 255) / 256, 256, 0, stream>>>(d_in[0], mic_f, 2250000);
  cvt_f<<<(640000 + 255) / 256, 256, 0, stream>>>(d_in[1], dis_f, 640000);
  cvt_f_t<<<(192000 + 255) / 256, 256, 0, stream>>>(d_in[6], WmT_f, 1500, 128);
  cvt_f_t<<<(102400 + 255) / 256, 256, 0, stream>>>(d_in[7], WdT_f, 800, 128);
  cvt_f_t<<<(131072 + 255) / 256, 256, 0, stream>>>(d_in[8], WlT_f, 128, 1024);
  cvt_f_t<<<(131072 + 255) / 256, 256, 0, stream>>>(d_in[10], WrT_f, 128, 1024);
  // all small f32 conversions in one launch (12 blocks)
  cvt_batch_f<<<12, 256, 0, stream>>>(
      d_in[9], bl_f, d_in[11], br_f, d_in[12], att_f, d_in[13], gbias_f,
      d_in[14], cw1_f, d_in[15], cb1_f, d_in[16], cw4_f, d_in[17], cb4_f,
      d_in[18], cw16_f, d_in[19], cb16_f, d_in[20], cw32_f, d_in[21], cb32_f);
  cvt_b_tt<<<dim3(88, 48), 256, 0, stream>>>(d_in[22], m1T, 2778, 1389, 2816,
                                             1536);
  cvt_b_tt<<<dim3(44, 24), 256, 0, stream>>>(d_in[24], m2T, 1389, 694, 1408,
                                             768);
  cvt_b_tt<<<dim3(24, 16), 256, 0, stream>>>(d_in[26], m3T, 694, 463, 768, 512);
  // all small bf16 conversions in one launch (4 blocks)
  cvt_batch_b<<<4, 256, 0, stream>>>(d_in[23], mb1_b, d_in[25], mb2_b,
                                     d_in[27], mb3_b, d_in[28], mw4_b);

  // ---- front end ----
  // mic/dis: K-split (chunk 192) into pre-zeroed hbuf via atomicAdd
  vgemm_ks<<<dim3(2, 94, 8), 256, 0, stream>>>(mic_f, WmT_f, hbuf, 1500, 128,
                                               1500, 1500, 1500, 128, 192);
  vgemm_ks<<<dim3(2, 50, 5), 256, 0, stream>>>(dis_f, WdT_f,
                                               hbuf + (size_t)1500 * 128, 800,
                                               128, 800, 800, 800, 128, 192);
  vgemm_f<<<dim3(16, 144), 256, 0, stream>>>(hbuf, WlT_f, bl_f, xlf, 2300,
                                             1024, 128, 128, 128, 1024);
  vgemm_f<<<dim3(16, 144), 256, 0, stream>>>(hbuf, WrT_f, br_f, xrf, 2300,
                                             1024, 128, 128, 128, 1024);

  k_edge_e<<<(ET + 3) / 4, 256, 0, stream>>>(xlf, xrf, ei, att_f, ebuf, E, ET);
  k_count<<<(ET + 255) / 256, 256, 0, stream>>>(ei, cnt, E, ET);
  k_scan<<<1, 256, 0, stream>>>(cnt, rowst, 2300);
  k_scatter<<<(ET + 255) / 256, 256, 0, stream>>>(ei, rowst, cur, csr, E, ET);
  k_softmax<<<(2300 + 3) / 4, 256, 0, stream>>>(ebuf, csr, rowst, wbuf, 2300, ET);
  k_aggregate<<<2300, 256, 0, stream>>>(wbuf, xlf, ei, csr, rowst, gbias_f,
                                        resf, E, ET);

  k_cnn<<<2300, 256, 0, stream>>>(resf, cw1_f, cb1_f, cw4_f, cb4_f, cw16_f,
                                  cb16_f, cw32_f, cb32_f, outc, emb);

  // ---- MLP: feats precompute + 8-phase 256-tile MFMA GEMMs, chunked ----
  for (int c0 = 0; c0 < M; c0 += R) {
    int rows = (M - c0 < R) ? (M - c0) : R;
    int gby = (rows + 255) / 256;
    k_feats<<<((size_t)rows * 352 + 255) / 256, 256, 0, stream>>>(
        emb, posp, negp, P, c0, rows, feats);
    mgemm256<<<dim3(6, gby), 512, 0, stream>>>(feats, m1T, mb1_b, hh1, rows,
                                               1389, 2816, 2816, 2816, 1408,
                                               0.01f);
    mgemm256<<<dim3(3, gby), 512, 0, stream>>>(hh1, m2T, mb2_b, hh2, rows, 694,
                                               1408, 1408, 1408, 768, 0.01f);
    mgemm256<<<dim3(2, gby), 512, 0, stream>>>(hh2, m3T, mb3_b, hh1, rows, 463,
                                               768, 768, 768, 480, 0.01f);
    k_gemv_sig<<<(rows + 3) / 4, 256, 0, stream>>>(hh1, mw4_b, outp + c0, rows,
                                                   463, 480);
  }
}